// Round 2
// baseline (1714.805 us; speedup 1.0000x reference)
//
#include <hip/hip_runtime.h>
#include <math.h>

// ---------------------------------------------------------------------------
// Sinkhorn ETP (FASTopic) on MI355X.
// n=256 topics, m=32768 words, D=384.
//
// State reduction (derived from the reference):
//   log_K0[i,j] = G[i,j] + su0[i] + sv0[j],  G = 40 * x@y^T
//   Per iteration:  L1[j] = lse_i(G+su);  W[j] = log_b - L1[j]
//                   L2[i] = lse_j(G+W);   su'[i] = log_a - L2[i]
//   (identical for keep and absorb; absorb adds the column-marginal error
//    check col[j] = exp(lse_i(G+su') + W[j]); row marginal error is 0.)
//   Final: transp[i,j] = exp(G+su[i]+W[j]); M = nx[i]+ny[j]-0.05*G;
//          loss = sum(transp*M)
// ---------------------------------------------------------------------------

#define N_TOPIC 256
#define N_WORD  32768

static constexpr float LOG_A = -5.545177444479562f;    // log(1/256 + 1e-30)
static constexpr float LOG_B = -10.397207708399179f;   // log(1/32768 + 1e-30)
static constexpr float BVAL  = 3.0517578125e-05f;      // 1/32768

// ---------------------------------------------------------------- init ------
__global__ __launch_bounds__(256) void init_k(
    const float* __restrict__ x, const float* __restrict__ y,
    float* __restrict__ nx, float* __restrict__ ny, float* __restrict__ su,
    unsigned* __restrict__ colerr, int* __restrict__ active, float* __restrict__ out)
{
    const int b = blockIdx.x, t = threadIdx.x;
    const int w = t >> 6, l = t & 63;
    if (b < 8192) {                       // ||y_j||^2, 4 rows/block (wave per row)
        const int r = (b << 2) + w;
        const float4* y4 = (const float4*)y;
        float4 v = y4[r * 96 + l];
        float s = v.x * v.x + v.y * v.y + v.z * v.z + v.w * v.w;
        if (l < 32) {
            float4 u = y4[r * 96 + 64 + l];
            s += u.x * u.x + u.y * u.y + u.z * u.z + u.w * u.w;
        }
        for (int off = 32; off; off >>= 1) s += __shfl_down(s, off);
        if (l == 0) ny[r] = s;
    } else if (b < 8256) {                // ||x_i||^2 and su0 = -20*nx
        const int r = ((b - 8192) << 2) + w;
        const float4* x4 = (const float4*)x;
        float4 v = x4[r * 96 + l];
        float s = v.x * v.x + v.y * v.y + v.z * v.z + v.w * v.w;
        if (l < 32) {
            float4 u = x4[r * 96 + 64 + l];
            s += u.x * u.x + u.y * u.y + u.z * u.z + u.w * u.w;
        }
        for (int off = 32; off; off >>= 1) s += __shfl_down(s, off);
        if (l == 0) { nx[r] = s; su[r] = -20.f * s; }
    } else {
        if (t == 0) { colerr[0] = 0u; colerr[1] = 0u; active[0] = 1; out[0] = 0.f; }
    }
}

// ---------------------------------------------------------------- gemm ------
// G[i,j] = 40 * dot(x_i, y_j).  LDS-tiled fp32 GEMM.
// Block tile: 64 i x 128 j, K-chunks of 32. Grid (256 jb, 4 ib) = 1024 blocks
// = 4 blocks/CU. Per thread: 4i x 8j accumulators; thread's j are tx+16c
// (interleaved) so LDS y-reads are conflict-free and global stores stay
// coalesced in 16-lane runs.
// LDS row stride 36 floats (16B-aligned float4 writes; compute reads are
// broadcast (x) / 2-way (y) -> conflict-free per m136.
__global__ __launch_bounds__(256, 4) void gemm_k(
    const float* __restrict__ x, const float* __restrict__ y, float* __restrict__ G)
{
    __shared__ float xs[64 * 36];
    __shared__ float ys[128 * 36];
    const int t   = threadIdx.x;
    const int tx  = t & 15;          // j lane
    const int ty  = t >> 4;          // i group (0..15), rows ty*4..ty*4+3
    const int jb  = blockIdx.x << 7; // 128-col slab
    const int i0B = blockIdx.y << 6; // 64-row slab

    const float4* x4 = (const float4*)x;
    const float4* y4 = (const float4*)y;
    float4* xs4 = (float4*)xs;
    float4* ys4 = (float4*)ys;

    // load indices (per chunk): x-tile 512 float4 (2/thread), y-tile 1024 (4/thread)
    const int xr0 = t >> 3, xq = t & 7;          // x: rows t>>3 and t>>3 + 32
    float acc[4][8];
#pragma unroll
    for (int a = 0; a < 4; ++a)
#pragma unroll
        for (int c = 0; c < 8; ++c) acc[a][c] = 0.f;

    // preload chunk 0 into registers
    float4 xr[2], yr[4];
#pragma unroll
    for (int p = 0; p < 2; ++p)
        xr[p] = x4[(i0B + xr0 + 32 * p) * 96 + xq];
#pragma unroll
    for (int p = 0; p < 4; ++p)
        yr[p] = y4[(jb + xr0 + 32 * p) * 96 + xq];

    for (int kc = 0; kc < 12; ++kc) {
        __syncthreads();   // prev compute done; LDS reusable
#pragma unroll
        for (int p = 0; p < 2; ++p)
            xs4[(xr0 + 32 * p) * 9 + xq] = xr[p];
#pragma unroll
        for (int p = 0; p < 4; ++p)
            ys4[(xr0 + 32 * p) * 9 + xq] = yr[p];
        __syncthreads();
        if (kc < 11) {     // prefetch next chunk while computing this one
            const int ko = (kc + 1) << 3;
#pragma unroll
            for (int p = 0; p < 2; ++p)
                xr[p] = x4[(i0B + xr0 + 32 * p) * 96 + ko + xq];
#pragma unroll
            for (int p = 0; p < 4; ++p)
                yr[p] = y4[(jb + xr0 + 32 * p) * 96 + ko + xq];
        }
#pragma unroll
        for (int k4 = 0; k4 < 8; ++k4) {
            float4 xa[4], yc[8];
#pragma unroll
            for (int a = 0; a < 4; ++a) xa[a] = xs4[(ty * 4 + a) * 9 + k4];
#pragma unroll
            for (int c = 0; c < 8; ++c) yc[c] = ys4[(tx + 16 * c) * 9 + k4];
#pragma unroll
            for (int a = 0; a < 4; ++a)
#pragma unroll
                for (int c = 0; c < 8; ++c)
                    acc[a][c] += xa[a].x * yc[c].x + xa[a].y * yc[c].y +
                                 xa[a].z * yc[c].z + xa[a].w * yc[c].w;
        }
    }
#pragma unroll
    for (int a = 0; a < 4; ++a) {
        const int gi = i0B + ty * 4 + a;
#pragma unroll
        for (int c = 0; c < 8; ++c)
            G[(size_t)gi * 32768 + jb + tx + 16 * c] = 40.f * acc[a][c];
    }
}

// ------------------------------------------------------------ iteration -----
// One fused Sinkhorn iteration pass. Block b owns columns [64b, 64b+64).
// Each thread caches a 16(row-strided) x 4(col) register tile of G.
__global__ __launch_bounds__(256) void sink_iter(
    const float* __restrict__ G, const float* __restrict__ su,
    float* __restrict__ W, float* __restrict__ pmT, float* __restrict__ psT,
    const int* __restrict__ active, int gated)
{
    if (gated && active[0] == 0) return;
    __shared__ float su_lds[256];
    __shared__ float comb[1024];
    __shared__ float Mlds[64];
    __shared__ float Wlds[64];
    __shared__ float m_arr[256 * 17];
    __shared__ float s_arr[256 * 17];

    const int t  = threadIdx.x;
    const int b  = blockIdx.x;
    const int j0 = b << 6;
    const int jq = t & 15;       // column quad 0..15 (4 cols each)
    const int is = t >> 4;       // row subset 0..15 (rows is+16k)

    su_lds[t] = su[t];
    __syncthreads();

    const float4* G4 = (const float4*)G;
    float4 tile[16];
    float  sur[16];
#pragma unroll
    for (int k = 0; k < 16; ++k) {
        int i = is + (k << 4);
        tile[k] = G4[i * 8192 + (j0 >> 2) + jq];
        sur[k]  = su_lds[i];
    }

    // ---- phase C: column logsumexp over i (exact two-pass from registers)
    float m0 = -INFINITY, m1 = -INFINITY, m2 = -INFINITY, m3 = -INFINITY;
#pragma unroll
    for (int k = 0; k < 16; ++k) {
        m0 = fmaxf(m0, tile[k].x + sur[k]);
        m1 = fmaxf(m1, tile[k].y + sur[k]);
        m2 = fmaxf(m2, tile[k].z + sur[k]);
        m3 = fmaxf(m3, tile[k].w + sur[k]);
    }
    ((float4*)comb)[(is << 4) + jq] = make_float4(m0, m1, m2, m3);
    __syncthreads();
    if (t < 64) {
        float m = -INFINITY;
#pragma unroll
        for (int s = 0; s < 16; ++s) m = fmaxf(m, comb[(s << 6) + t]);
        Mlds[t] = m;
    }
    __syncthreads();
    float4 Mq = make_float4(Mlds[4 * jq + 0], Mlds[4 * jq + 1],
                            Mlds[4 * jq + 2], Mlds[4 * jq + 3]);
    float s0 = 0.f, s1 = 0.f, s2 = 0.f, s3 = 0.f;
#pragma unroll
    for (int k = 0; k < 16; ++k) {
        s0 += __expf(tile[k].x + sur[k] - Mq.x);
        s1 += __expf(tile[k].y + sur[k] - Mq.y);
        s2 += __expf(tile[k].z + sur[k] - Mq.z);
        s3 += __expf(tile[k].w + sur[k] - Mq.w);
    }
    ((float4*)comb)[(is << 4) + jq] = make_float4(s0, s1, s2, s3);
    __syncthreads();
    if (t < 64) {
        float ssum = 0.f;
#pragma unroll
        for (int s = 0; s < 16; ++s) ssum += comb[(s << 6) + t];
        float Wj = LOG_B - (Mlds[t] + __logf(ssum));
        Wlds[t] = Wj;
        W[j0 + t] = Wj;
    }
    __syncthreads();
    float4 Wq = make_float4(Wlds[4 * jq + 0], Wlds[4 * jq + 1],
                            Wlds[4 * jq + 2], Wlds[4 * jq + 3]);

    // ---- phase R: per-row partial lse over this block's 64 columns
#pragma unroll
    for (int k = 0; k < 16; ++k) {
        float a0 = tile[k].x + Wq.x;
        float a1 = tile[k].y + Wq.y;
        float a2 = tile[k].z + Wq.z;
        float a3 = tile[k].w + Wq.w;
        float m = fmaxf(fmaxf(a0, a1), fmaxf(a2, a3));
        float s = __expf(a0 - m) + __expf(a1 - m) + __expf(a2 - m) + __expf(a3 - m);
        int i = is + (k << 4);
        m_arr[i * 17 + jq] = m;   // stride 17: ~2-way banks only
        s_arr[i * 17 + jq] = s;
    }
    __syncthreads();
    {   // thread t combines the 16 column-quad partials of row t
        float m = -INFINITY, s = 0.f;
#pragma unroll
        for (int p = 0; p < 16; ++p) {
            float pm = m_arr[t * 17 + p];
            float ps = s_arr[t * 17 + p];
            float nm = fmaxf(m, pm);
            s = s * __expf(m - nm) + ps * __expf(pm - nm);
            m = nm;
        }
        pmT[(t << 9) + b] = m;    // [row][block] layout -> coalesced combine
        psT[(t << 9) + b] = s;
    }
}

// ------------------------------------------------- row-partial combine ------
// block i: exact lse-combine of 512 block partials -> su'[i] = log_a - L2[i]
__global__ __launch_bounds__(64) void sink_combine(
    const float* __restrict__ pmT, const float* __restrict__ psT,
    float* __restrict__ su, const int* __restrict__ active, int gated)
{
    if (gated && active[0] == 0) return;
    const int i = blockIdx.x, p = threadIdx.x;
    float m = -INFINITY, s = 0.f;
#pragma unroll
    for (int q = 0; q < 8; ++q) {
        float pm = pmT[(i << 9) + p + (q << 6)];
        float ps = psT[(i << 9) + p + (q << 6)];
        float nm = fmaxf(m, pm);
        s = s * __expf(m - nm) + ps * __expf(pm - nm);
        m = nm;
    }
    for (int off = 32; off; off >>= 1) {
        float om = __shfl_down(m, off);
        float os = __shfl_down(s, off);
        float nm = fmaxf(m, om);
        s = s * __expf(m - nm) + os * __expf(om - nm);
        m = nm;
    }
    if (p == 0) su[i] = LOG_A - (m + __logf(s));
}

// --------------------------------------------- absorb-step column error -----
// col[j] = exp(lse_i(G+su') + W[j]);  err_col = max_j |col - b|.
__global__ __launch_bounds__(256) void sink_colerr(
    const float* __restrict__ G, const float* __restrict__ su,
    const float* __restrict__ W, unsigned* __restrict__ colerr, int slot,
    const int* __restrict__ active, int gated)
{
    if (gated && active[0] == 0) return;
    __shared__ float su_lds[256];
    __shared__ float comb[1024];
    __shared__ float Mlds[64];

    const int t  = threadIdx.x;
    const int b  = blockIdx.x;
    const int j0 = b << 6;
    const int jq = t & 15;
    const int is = t >> 4;

    su_lds[t] = su[t];
    __syncthreads();

    const float4* G4 = (const float4*)G;
    float4 tile[16];
    float  sur[16];
#pragma unroll
    for (int k = 0; k < 16; ++k) {
        int i = is + (k << 4);
        tile[k] = G4[i * 8192 + (j0 >> 2) + jq];
        sur[k]  = su_lds[i];
    }
    float m0 = -INFINITY, m1 = -INFINITY, m2 = -INFINITY, m3 = -INFINITY;
#pragma unroll
    for (int k = 0; k < 16; ++k) {
        m0 = fmaxf(m0, tile[k].x + sur[k]);
        m1 = fmaxf(m1, tile[k].y + sur[k]);
        m2 = fmaxf(m2, tile[k].z + sur[k]);
        m3 = fmaxf(m3, tile[k].w + sur[k]);
    }
    ((float4*)comb)[(is << 4) + jq] = make_float4(m0, m1, m2, m3);
    __syncthreads();
    if (t < 64) {
        float m = -INFINITY;
#pragma unroll
        for (int s = 0; s < 16; ++s) m = fmaxf(m, comb[(s << 6) + t]);
        Mlds[t] = m;
    }
    __syncthreads();
    float4 Mq = make_float4(Mlds[4 * jq + 0], Mlds[4 * jq + 1],
                            Mlds[4 * jq + 2], Mlds[4 * jq + 3]);
    float s0 = 0.f, s1 = 0.f, s2 = 0.f, s3 = 0.f;
#pragma unroll
    for (int k = 0; k < 16; ++k) {
        s0 += __expf(tile[k].x + sur[k] - Mq.x);
        s1 += __expf(tile[k].y + sur[k] - Mq.y);
        s2 += __expf(tile[k].z + sur[k] - Mq.z);
        s3 += __expf(tile[k].w + sur[k] - Mq.w);
    }
    ((float4*)comb)[(is << 4) + jq] = make_float4(s0, s1, s2, s3);
    __syncthreads();
    if (t < 64) {
        float ssum = 0.f;
#pragma unroll
        for (int s = 0; s < 16; ++s) ssum += comb[(s << 6) + t];
        float Aj  = Mlds[t] + __logf(ssum);
        float col = __expf(Aj + W[j0 + t]);
        float d   = fabsf(col - BVAL);
        for (int off = 32; off; off >>= 1) d = fmaxf(d, __shfl_down(d, off));
        if (t == 0) atomicMax(colerr + slot, __float_as_uint(d));  // d >= 0
    }
}

__global__ void sink_check(const unsigned* __restrict__ colerr, int slot,
                           int* __restrict__ active)
{
    if (threadIdx.x == 0)
        active[0] = (__uint_as_float(colerr[slot]) > 0.005f) ? 1 : 0;
}

// ------------------------------------------------------------- finalize -----
__global__ __launch_bounds__(256) void finalize_k(
    const float* __restrict__ G, const float* __restrict__ su,
    const float* __restrict__ W, const float* __restrict__ nx,
    const float* __restrict__ ny, float* __restrict__ out)
{
    __shared__ float su_lds[256], nx_lds[256];
    __shared__ float red[4];
    const int t = threadIdx.x, b = blockIdx.x;
    const int j0 = b << 6;
    su_lds[t] = su[t];
    nx_lds[t] = nx[t];
    __syncthreads();
    const int jj = t & 63, ig = t >> 6;
    const int j = j0 + jj;
    const float Wj = W[j], nyj = ny[j];
    float acc = 0.f;
#pragma unroll 4
    for (int k = 0; k < 64; ++k) {
        int i = ig + (k << 2);
        float g = G[i * 32768 + j];
        float v = __expf(g + su_lds[i] + Wj);
        out[1 + (size_t)i * 32768 + j] = v;
        acc += v * (nx_lds[i] + nyj - 0.05f * g);
    }
    for (int off = 32; off; off >>= 1) acc += __shfl_down(acc, off);
    if ((t & 63) == 0) red[t >> 6] = acc;
    __syncthreads();
    if (t == 0) atomicAdd(out, red[0] + red[1] + red[2] + red[3]);
}

// ---------------------------------------------------------------- host ------
extern "C" void kernel_launch(void* const* d_in, const int* in_sizes, int n_in,
                              void* d_out, int out_size, void* d_ws, size_t ws_size,
                              hipStream_t stream)
{
    const float* x = (const float*)d_in[0];   // [256, 384]
    const float* y = (const float*)d_in[1];   // [32768, 384]
    float* out = (float*)d_out;               // [1 + 256*32768]

    float* ws   = (float*)d_ws;
    float* G    = ws;                 // 8388608
    float* Wv   = G + 8388608;        // 32768
    float* su   = Wv + 32768;         // 256
    float* nx   = su + 256;           // 256
    float* ny   = nx + 256;           // 32768
    float* pmT  = ny + 32768;         // 131072  [row][block]
    float* psT  = pmT + 131072;       // 131072
    unsigned* colerr = (unsigned*)(psT + 131072);  // 2
    int* active = (int*)(colerr + 2);              // 1

    init_k<<<8257, 256, 0, stream>>>(x, y, nx, ny, su, colerr, active, out);
    gemm_k<<<dim3(256, 4), 256, 0, stream>>>(x, y, G);

    // iteration 1 (always runs) + absorb error check
    sink_iter<<<512, 256, 0, stream>>>(G, su, Wv, pmT, psT, active, 0);
    sink_combine<<<256, 64, 0, stream>>>(pmT, psT, su, active, 0);
    sink_colerr<<<512, 256, 0, stream>>>(G, su, Wv, colerr, 0, active, 0);
    sink_check<<<1, 64, 0, stream>>>(colerr, 0, active);

    for (int tt = 2; tt <= 100; ++tt) {
        sink_iter<<<512, 256, 0, stream>>>(G, su, Wv, pmT, psT, active, 1);
        sink_combine<<<256, 64, 0, stream>>>(pmT, psT, su, active, 1);
        if (tt == 51) {   // absorb at cpt_n=51: error check gates the rest
            sink_colerr<<<512, 256, 0, stream>>>(G, su, Wv, colerr, 1, active, 1);
            sink_check<<<1, 64, 0, stream>>>(colerr, 1, active);
        }
    }

    finalize_k<<<512, 256, 0, stream>>>(G, su, Wv, nx, ny, out);
}

// Round 3
// 804.255 us; speedup vs baseline: 2.1322x; 2.1322x over previous
//
#include <hip/hip_runtime.h>
#include <math.h>

// ---------------------------------------------------------------------------
// Sinkhorn ETP (FASTopic) on MI355X.
// n=256 topics, m=32768 words, D=384.
//
// State reduction (derived from the reference):
//   log_K0[i,j] = G[i,j] + su0[i] + sv0[j],  G = 40 * x@y^T
//   Per iteration:  L1[j] = lse_i(G+su);  W[j] = log_b - L1[j]
//                   L2[i] = lse_j(G+W);   su'[i] = log_a - L2[i]
//   (identical for keep and absorb; absorb adds the column-marginal error
//    check col[j] = exp(lse_i(G+su') + W[j]); row marginal error is 0.)
//   Final: transp[i,j] = exp(G+su[i]+W[j]); M = nx[i]+ny[j]-0.05*G;
//          loss = sum(transp*M)
// ---------------------------------------------------------------------------

#define N_TOPIC 256
#define N_WORD  32768

static constexpr float LOG_A = -5.545177444479562f;    // log(1/256 + 1e-30)
static constexpr float LOG_B = -10.397207708399179f;   // log(1/32768 + 1e-30)
static constexpr float BVAL  = 3.0517578125e-05f;      // 1/32768

// ---------------------------------------------------------------- init ------
__global__ __launch_bounds__(256) void init_k(
    const float* __restrict__ x, const float* __restrict__ y,
    float* __restrict__ nx, float* __restrict__ ny, float* __restrict__ su,
    unsigned* __restrict__ colerr, int* __restrict__ active,
    int* __restrict__ counters, float* __restrict__ out)
{
    const int b = blockIdx.x, t = threadIdx.x;
    const int w = t >> 6, l = t & 63;
    if (b < 8192) {                       // ||y_j||^2, 4 rows/block (wave per row)
        const int r = (b << 2) + w;
        const float4* y4 = (const float4*)y;
        float4 v = y4[r * 96 + l];
        float s = v.x * v.x + v.y * v.y + v.z * v.z + v.w * v.w;
        if (l < 32) {
            float4 u = y4[r * 96 + 64 + l];
            s += u.x * u.x + u.y * u.y + u.z * u.z + u.w * u.w;
        }
        for (int off = 32; off; off >>= 1) s += __shfl_down(s, off);
        if (l == 0) ny[r] = s;
    } else if (b < 8256) {                // ||x_i||^2 and su0 = -20*nx
        const int r = ((b - 8192) << 2) + w;
        const float4* x4 = (const float4*)x;
        float4 v = x4[r * 96 + l];
        float s = v.x * v.x + v.y * v.y + v.z * v.z + v.w * v.w;
        if (l < 32) {
            float4 u = x4[r * 96 + 64 + l];
            s += u.x * u.x + u.y * u.y + u.z * u.z + u.w * u.w;
        }
        for (int off = 32; off; off >>= 1) s += __shfl_down(s, off);
        if (l == 0) { nx[r] = s; su[r] = -20.f * s; }
    } else {
        if (t < 128) counters[t] = 0;     // per-iteration last-block counters
        if (t == 0) { colerr[0] = 0u; colerr[1] = 0u; active[0] = 1; out[0] = 0.f; }
    }
}

// ---------------------------------------------------------------- gemm ------
// G[i,j] = 40 * dot(x_i, y_j).  LDS-tiled fp32 GEMM, 64i x 128j block tile,
// K-chunks of 32, register prefetch. Per thread 4i x 8j acc (~114 live VGPRs).
// __launch_bounds__(256,2): R2's (256,4) clamped VGPRs to 64 -> 2.7 GB of
// scratch-spill traffic. Cap must stay >= ~128.
__global__ __launch_bounds__(256, 2) void gemm_k(
    const float* __restrict__ x, const float* __restrict__ y, float* __restrict__ G)
{
    __shared__ float xs[64 * 36];
    __shared__ float ys[128 * 36];
    const int t   = threadIdx.x;
    const int tx  = t & 15;          // j lane
    const int ty  = t >> 4;          // i group (0..15), rows ty*4..ty*4+3
    const int jb  = blockIdx.x << 7; // 128-col slab
    const int i0B = blockIdx.y << 6; // 64-row slab

    const float4* x4 = (const float4*)x;
    const float4* y4 = (const float4*)y;
    float4* xs4 = (float4*)xs;
    float4* ys4 = (float4*)ys;

    const int xr0 = t >> 3, xq = t & 7;
    float acc[4][8];
#pragma unroll
    for (int a = 0; a < 4; ++a)
#pragma unroll
        for (int c = 0; c < 8; ++c) acc[a][c] = 0.f;

    float4 xr[2], yr[4];
#pragma unroll
    for (int p = 0; p < 2; ++p)
        xr[p] = x4[(i0B + xr0 + 32 * p) * 96 + xq];
#pragma unroll
    for (int p = 0; p < 4; ++p)
        yr[p] = y4[(jb + xr0 + 32 * p) * 96 + xq];

    for (int kc = 0; kc < 12; ++kc) {
        __syncthreads();
#pragma unroll
        for (int p = 0; p < 2; ++p)
            xs4[(xr0 + 32 * p) * 9 + xq] = xr[p];
#pragma unroll
        for (int p = 0; p < 4; ++p)
            ys4[(xr0 + 32 * p) * 9 + xq] = yr[p];
        __syncthreads();
        if (kc < 11) {
            const int ko = (kc + 1) << 3;
#pragma unroll
            for (int p = 0; p < 2; ++p)
                xr[p] = x4[(i0B + xr0 + 32 * p) * 96 + ko + xq];
#pragma unroll
            for (int p = 0; p < 4; ++p)
                yr[p] = y4[(jb + xr0 + 32 * p) * 96 + ko + xq];
        }
#pragma unroll
        for (int k4 = 0; k4 < 8; ++k4) {
            float4 xa[4], yc[8];
#pragma unroll
            for (int a = 0; a < 4; ++a) xa[a] = xs4[(ty * 4 + a) * 9 + k4];
#pragma unroll
            for (int c = 0; c < 8; ++c) yc[c] = ys4[(tx + 16 * c) * 9 + k4];
#pragma unroll
            for (int a = 0; a < 4; ++a)
#pragma unroll
                for (int c = 0; c < 8; ++c)
                    acc[a][c] += xa[a].x * yc[c].x + xa[a].y * yc[c].y +
                                 xa[a].z * yc[c].z + xa[a].w * yc[c].w;
        }
    }
#pragma unroll
    for (int a = 0; a < 4; ++a) {
        const int gi = i0B + ty * 4 + a;
#pragma unroll
        for (int c = 0; c < 8; ++c)
            G[(size_t)gi * 32768 + jb + tx + 16 * c] = 40.f * acc[a][c];
    }
}

// ------------------------------------------------------------ iteration -----
// One fused Sinkhorn iteration. Block b owns columns [64b, 64b+64).
// Each thread caches a 16(row-strided) x 4(col) register tile of G.
// Last block (device-scope counter) combines all 512 row-partials -> su'.
__global__ __launch_bounds__(256) void sink_step(
    const float* __restrict__ G, float* __restrict__ su,
    float* __restrict__ W, float* __restrict__ pmT, float* __restrict__ psT,
    int* __restrict__ counter, const int* __restrict__ active, int gated)
{
    if (gated && active[0] == 0) return;
    __shared__ float su_lds[256];
    __shared__ float comb[1024];
    __shared__ float Mlds[64];
    __shared__ float Wlds[64];
    __shared__ float m_arr[256 * 17];
    __shared__ float s_arr[256 * 17];
    __shared__ int lastf;

    const int t  = threadIdx.x;
    const int b  = blockIdx.x;
    const int j0 = b << 6;
    const int jq = t & 15;       // column quad 0..15 (4 cols each)
    const int is = t >> 4;       // row subset 0..15 (rows is+16k)

    su_lds[t] = su[t];
    __syncthreads();

    const float4* G4 = (const float4*)G;
    float4 tile[16];
    float  sur[16];
#pragma unroll
    for (int k = 0; k < 16; ++k) {
        int i = is + (k << 4);
        tile[k] = G4[i * 8192 + (j0 >> 2) + jq];
        sur[k]  = su_lds[i];
    }

    // ---- phase C: column logsumexp over i (exact two-pass from registers)
    float m0 = -INFINITY, m1 = -INFINITY, m2 = -INFINITY, m3 = -INFINITY;
#pragma unroll
    for (int k = 0; k < 16; ++k) {
        m0 = fmaxf(m0, tile[k].x + sur[k]);
        m1 = fmaxf(m1, tile[k].y + sur[k]);
        m2 = fmaxf(m2, tile[k].z + sur[k]);
        m3 = fmaxf(m3, tile[k].w + sur[k]);
    }
    ((float4*)comb)[(is << 4) + jq] = make_float4(m0, m1, m2, m3);
    __syncthreads();
    if (t < 64) {
        float m = -INFINITY;
#pragma unroll
        for (int s = 0; s < 16; ++s) m = fmaxf(m, comb[(s << 6) + t]);
        Mlds[t] = m;
    }
    __syncthreads();
    float4 Mq = make_float4(Mlds[4 * jq + 0], Mlds[4 * jq + 1],
                            Mlds[4 * jq + 2], Mlds[4 * jq + 3]);
    float s0 = 0.f, s1 = 0.f, s2 = 0.f, s3 = 0.f;
#pragma unroll
    for (int k = 0; k < 16; ++k) {
        s0 += __expf(tile[k].x + sur[k] - Mq.x);
        s1 += __expf(tile[k].y + sur[k] - Mq.y);
        s2 += __expf(tile[k].z + sur[k] - Mq.z);
        s3 += __expf(tile[k].w + sur[k] - Mq.w);
    }
    ((float4*)comb)[(is << 4) + jq] = make_float4(s0, s1, s2, s3);
    __syncthreads();
    if (t < 64) {
        float ssum = 0.f;
#pragma unroll
        for (int s = 0; s < 16; ++s) ssum += comb[(s << 6) + t];
        float Wj = LOG_B - (Mlds[t] + __logf(ssum));
        Wlds[t] = Wj;
        W[j0 + t] = Wj;
    }
    __syncthreads();
    float4 Wq = make_float4(Wlds[4 * jq + 0], Wlds[4 * jq + 1],
                            Wlds[4 * jq + 2], Wlds[4 * jq + 3]);

    // ---- phase R: per-row partial lse over this block's 64 columns
#pragma unroll
    for (int k = 0; k < 16; ++k) {
        float a0 = tile[k].x + Wq.x;
        float a1 = tile[k].y + Wq.y;
        float a2 = tile[k].z + Wq.z;
        float a3 = tile[k].w + Wq.w;
        float m = fmaxf(fmaxf(a0, a1), fmaxf(a2, a3));
        float s = __expf(a0 - m) + __expf(a1 - m) + __expf(a2 - m) + __expf(a3 - m);
        int i = is + (k << 4);
        m_arr[i * 17 + jq] = m;   // stride 17: 2-way banks only (free, m136)
        s_arr[i * 17 + jq] = s;
    }
    __syncthreads();
    {   // thread t combines the 16 column-quad partials of row t
        float m = -INFINITY, s = 0.f;
#pragma unroll
        for (int p = 0; p < 16; ++p) {
            float pm = m_arr[t * 17 + p];
            float ps = s_arr[t * 17 + p];
            float nm = fmaxf(m, pm);
            s = s * __expf(m - nm) + ps * __expf(pm - nm);
            m = nm;
        }
        pmT[(t << 9) + b] = m;    // [row][block] layout: combine streams rows
        psT[(t << 9) + b] = s;
    }

    // ---- last-block combine (threadfence reduction, device scope)
    __threadfence();                       // release: partials -> device scope
    if (t == 0) lastf = (atomicAdd(counter, 1) == 511);
    __syncthreads();
    if (!lastf) return;
    __threadfence();                       // acquire: invalidate stale caches

    {   // thread t: row t, 512 partials, 4 interleaved lse chains for ILP
        const float* pm = pmT + (t << 9);
        const float* ps = psT + (t << 9);
        float cm[4] = {-INFINITY, -INFINITY, -INFINITY, -INFINITY};
        float cs[4] = {0.f, 0.f, 0.f, 0.f};
        for (int p = 0; p < 512; p += 4) {
#pragma unroll
            for (int c = 0; c < 4; ++c) {
                float pmv = pm[p + c], psv = ps[p + c];
                float nm = fmaxf(cm[c], pmv);
                cs[c] = cs[c] * __expf(cm[c] - nm) + psv * __expf(pmv - nm);
                cm[c] = nm;
            }
        }
        float m = cm[0], s = cs[0];
#pragma unroll
        for (int c = 1; c < 4; ++c) {
            float nm = fmaxf(m, cm[c]);
            s = s * __expf(m - nm) + cs[c] * __expf(cm[c] - nm);
            m = nm;
        }
        su[t] = LOG_A - (m + __logf(s));
    }
}

// --------------------------------------------- absorb-step column error -----
// col[j] = exp(lse_i(G+su') + W[j]);  err_col = max_j |col - b|.
__global__ __launch_bounds__(256) void sink_colerr(
    const float* __restrict__ G, const float* __restrict__ su,
    const float* __restrict__ W, unsigned* __restrict__ colerr, int slot,
    const int* __restrict__ active, int gated)
{
    if (gated && active[0] == 0) return;
    __shared__ float su_lds[256];
    __shared__ float comb[1024];
    __shared__ float Mlds[64];

    const int t  = threadIdx.x;
    const int b  = blockIdx.x;
    const int j0 = b << 6;
    const int jq = t & 15;
    const int is = t >> 4;

    su_lds[t] = su[t];
    __syncthreads();

    const float4* G4 = (const float4*)G;
    float4 tile[16];
    float  sur[16];
#pragma unroll
    for (int k = 0; k < 16; ++k) {
        int i = is + (k << 4);
        tile[k] = G4[i * 8192 + (j0 >> 2) + jq];
        sur[k]  = su_lds[i];
    }
    float m0 = -INFINITY, m1 = -INFINITY, m2 = -INFINITY, m3 = -INFINITY;
#pragma unroll
    for (int k = 0; k < 16; ++k) {
        m0 = fmaxf(m0, tile[k].x + sur[k]);
        m1 = fmaxf(m1, tile[k].y + sur[k]);
        m2 = fmaxf(m2, tile[k].z + sur[k]);
        m3 = fmaxf(m3, tile[k].w + sur[k]);
    }
    ((float4*)comb)[(is << 4) + jq] = make_float4(m0, m1, m2, m3);
    __syncthreads();
    if (t < 64) {
        float m = -INFINITY;
#pragma unroll
        for (int s = 0; s < 16; ++s) m = fmaxf(m, comb[(s << 6) + t]);
        Mlds[t] = m;
    }
    __syncthreads();
    float4 Mq = make_float4(Mlds[4 * jq + 0], Mlds[4 * jq + 1],
                            Mlds[4 * jq + 2], Mlds[4 * jq + 3]);
    float s0 = 0.f, s1 = 0.f, s2 = 0.f, s3 = 0.f;
#pragma unroll
    for (int k = 0; k < 16; ++k) {
        s0 += __expf(tile[k].x + sur[k] - Mq.x);
        s1 += __expf(tile[k].y + sur[k] - Mq.y);
        s2 += __expf(tile[k].z + sur[k] - Mq.z);
        s3 += __expf(tile[k].w + sur[k] - Mq.w);
    }
    ((float4*)comb)[(is << 4) + jq] = make_float4(s0, s1, s2, s3);
    __syncthreads();
    if (t < 64) {
        float ssum = 0.f;
#pragma unroll
        for (int s = 0; s < 16; ++s) ssum += comb[(s << 6) + t];
        float Aj  = Mlds[t] + __logf(ssum);
        float col = __expf(Aj + W[j0 + t]);
        float d   = fabsf(col - BVAL);
        for (int off = 32; off; off >>= 1) d = fmaxf(d, __shfl_down(d, off));
        if (t == 0) atomicMax(colerr + slot, __float_as_uint(d));  // d >= 0
    }
}

__global__ void sink_check(const unsigned* __restrict__ colerr, int slot,
                           int* __restrict__ active)
{
    if (threadIdx.x == 0)
        active[0] = (__uint_as_float(colerr[slot]) > 0.005f) ? 1 : 0;
}

// ------------------------------------------------------------- finalize -----
__global__ __launch_bounds__(256) void finalize_k(
    const float* __restrict__ G, const float* __restrict__ su,
    const float* __restrict__ W, const float* __restrict__ nx,
    const float* __restrict__ ny, float* __restrict__ out)
{
    __shared__ float su_lds[256], nx_lds[256];
    __shared__ float red[4];
    const int t = threadIdx.x, b = blockIdx.x;
    const int j0 = b << 6;
    su_lds[t] = su[t];
    nx_lds[t] = nx[t];
    __syncthreads();
    const int jj = t & 63, ig = t >> 6;
    const int j = j0 + jj;
    const float Wj = W[j], nyj = ny[j];
    float acc = 0.f;
#pragma unroll 4
    for (int k = 0; k < 64; ++k) {
        int i = ig + (k << 2);
        float g = G[i * 32768 + j];
        float v = __expf(g + su_lds[i] + Wj);
        out[1 + (size_t)i * 32768 + j] = v;
        acc += v * (nx_lds[i] + nyj - 0.05f * g);
    }
    for (int off = 32; off; off >>= 1) acc += __shfl_down(acc, off);
    if ((t & 63) == 0) red[t >> 6] = acc;
    __syncthreads();
    if (t == 0) atomicAdd(out, red[0] + red[1] + red[2] + red[3]);
}

// ---------------------------------------------------------------- host ------
extern "C" void kernel_launch(void* const* d_in, const int* in_sizes, int n_in,
                              void* d_out, int out_size, void* d_ws, size_t ws_size,
                              hipStream_t stream)
{
    const float* x = (const float*)d_in[0];   // [256, 384]
    const float* y = (const float*)d_in[1];   // [32768, 384]
    float* out = (float*)d_out;               // [1 + 256*32768]

    float* ws   = (float*)d_ws;
    float* G    = ws;                 // 8388608
    float* Wv   = G + 8388608;        // 32768
    float* su   = Wv + 32768;         // 256
    float* nx   = su + 256;           // 256
    float* ny   = nx + 256;           // 32768
    float* pmT  = ny + 32768;         // 131072  [row][block]
    float* psT  = pmT + 131072;       // 131072
    unsigned* colerr = (unsigned*)(psT + 131072);  // 2
    int* active   = (int*)(colerr + 2);            // 1
    int* counters = active + 1;                    // 128 (one per iteration)

    init_k<<<8257, 256, 0, stream>>>(x, y, nx, ny, su, colerr, active, counters, out);
    gemm_k<<<dim3(256, 4), 256, 0, stream>>>(x, y, G);

    // iteration 1 (always runs) + absorb error check
    sink_step<<<512, 256, 0, stream>>>(G, su, Wv, pmT, psT, counters + 0, active, 0);
    sink_colerr<<<512, 256, 0, stream>>>(G, su, Wv, colerr, 0, active, 0);
    sink_check<<<1, 64, 0, stream>>>(colerr, 0, active);

    for (int tt = 2; tt <= 100; ++tt) {
        sink_step<<<512, 256, 0, stream>>>(G, su, Wv, pmT, psT, counters + tt - 1, active, 1);
        if (tt == 51) {   // absorb at cpt_n=51: error check gates the rest
            sink_colerr<<<512, 256, 0, stream>>>(G, su, Wv, colerr, 1, active, 1);
            sink_check<<<1, 64, 0, stream>>>(colerr, 1, active);
        }
    }

    finalize_k<<<512, 256, 0, stream>>>(G, su, Wv, nx, ny, out);
}

// Round 4
// 599.588 us; speedup vs baseline: 2.8600x; 1.3413x over previous
//
#include <hip/hip_runtime.h>
#include <math.h>

// ---------------------------------------------------------------------------
// Sinkhorn ETP (FASTopic) on MI355X.
// n=256 topics, m=32768 words, D=384.
//
// State reduction (derived from the reference):
//   log_K0[i,j] = G[i,j] + su0[i] + sv0[j],  G = 40 * x@y^T
//   Per iteration:  L1[j] = lse_i(G+su);  W[j] = log_b - L1[j]
//                   L2[i] = lse_j(G+W);   su'[i] = log_a - L2[i]
//   (identical for keep and absorb; absorb adds the column-marginal error
//    check col[j] = exp(lse_i(G+su') + W[j]); row marginal error is 0.)
//   Final: transp[i,j] = exp(G+su[i]+W[j]); M = nx[i]+ny[j]-0.05*G;
//          loss = sum(transp*M)
// ---------------------------------------------------------------------------

#define N_TOPIC 256
#define N_WORD  32768

static constexpr float LOG_A = -5.545177444479562f;    // log(1/256 + 1e-30)
static constexpr float LOG_B = -10.397207708399179f;   // log(1/32768 + 1e-30)
static constexpr float BVAL  = 3.0517578125e-05f;      // 1/32768

// ---------------------------------------------------------------- init ------
__global__ __launch_bounds__(256) void init_k(
    const float* __restrict__ x, const float* __restrict__ y,
    float* __restrict__ nx, float* __restrict__ ny, float* __restrict__ su,
    unsigned* __restrict__ colerr, int* __restrict__ active,
    int* __restrict__ counters, float* __restrict__ out)
{
    const int b = blockIdx.x, t = threadIdx.x;
    const int w = t >> 6, l = t & 63;
    if (b < 8192) {                       // ||y_j||^2, 4 rows/block (wave per row)
        const int r = (b << 2) + w;
        const float4* y4 = (const float4*)y;
        float4 v = y4[r * 96 + l];
        float s = v.x * v.x + v.y * v.y + v.z * v.z + v.w * v.w;
        if (l < 32) {
            float4 u = y4[r * 96 + 64 + l];
            s += u.x * u.x + u.y * u.y + u.z * u.z + u.w * u.w;
        }
        for (int off = 32; off; off >>= 1) s += __shfl_down(s, off);
        if (l == 0) ny[r] = s;
    } else if (b < 8256) {                // ||x_i||^2 and su0 = -20*nx
        const int r = ((b - 8192) << 2) + w;
        const float4* x4 = (const float4*)x;
        float4 v = x4[r * 96 + l];
        float s = v.x * v.x + v.y * v.y + v.z * v.z + v.w * v.w;
        if (l < 32) {
            float4 u = x4[r * 96 + 64 + l];
            s += u.x * u.x + u.y * u.y + u.z * u.z + u.w * u.w;
        }
        for (int off = 32; off; off >>= 1) s += __shfl_down(s, off);
        if (l == 0) { nx[r] = s; su[r] = -20.f * s; }
    } else {
        if (t < 128) counters[t] = 0;     // per-iteration last-block counters
        if (t == 0) { colerr[0] = 0u; colerr[1] = 0u; active[0] = 1; out[0] = 0.f; }
    }
}

// ---------------------------------------------------------------- gemm ------
// G[i,j] = 40 * dot(x_i, y_j).  LDS-tiled fp32 GEMM, 64i x 128j block tile,
// K-chunks of 32, register prefetch. Per thread 4i x 8j acc.
// Spill history: (256,4)->64 VGPR, 2.7 GB spill; (256,2)->128 VGPR, 1.9 GB
// spill. Fix: (256,1) (cap 512, spill-impossible) + split the j-loop into
// 2 chunks of 4 so only yc[4] float4 are live (~100 live VGPRs).
__global__ __launch_bounds__(256, 1) void gemm_k(
    const float* __restrict__ x, const float* __restrict__ y, float* __restrict__ G)
{
    __shared__ float xs[64 * 36];
    __shared__ float ys[128 * 36];
    const int t   = threadIdx.x;
    const int tx  = t & 15;          // j lane
    const int ty  = t >> 4;          // i group (0..15), rows ty*4..ty*4+3
    const int jb  = blockIdx.x << 7; // 128-col slab
    const int i0B = blockIdx.y << 6; // 64-row slab

    const float4* x4 = (const float4*)x;
    const float4* y4 = (const float4*)y;
    float4* xs4 = (float4*)xs;
    float4* ys4 = (float4*)ys;

    const int xr0 = t >> 3, xq = t & 7;
    float acc[4][8];
#pragma unroll
    for (int a = 0; a < 4; ++a)
#pragma unroll
        for (int c = 0; c < 8; ++c) acc[a][c] = 0.f;

    float4 xr[2], yr[4];
#pragma unroll
    for (int p = 0; p < 2; ++p)
        xr[p] = x4[(i0B + xr0 + 32 * p) * 96 + xq];
#pragma unroll
    for (int p = 0; p < 4; ++p)
        yr[p] = y4[(jb + xr0 + 32 * p) * 96 + xq];

    for (int kc = 0; kc < 12; ++kc) {
        __syncthreads();
#pragma unroll
        for (int p = 0; p < 2; ++p)
            xs4[(xr0 + 32 * p) * 9 + xq] = xr[p];
#pragma unroll
        for (int p = 0; p < 4; ++p)
            ys4[(xr0 + 32 * p) * 9 + xq] = yr[p];
        __syncthreads();
        if (kc < 11) {
            const int ko = (kc + 1) << 3;
#pragma unroll
            for (int p = 0; p < 2; ++p)
                xr[p] = x4[(i0B + xr0 + 32 * p) * 96 + ko + xq];
#pragma unroll
            for (int p = 0; p < 4; ++p)
                yr[p] = y4[(jb + xr0 + 32 * p) * 96 + ko + xq];
        }
#pragma unroll
        for (int k4 = 0; k4 < 8; ++k4) {
            float4 xa[4];
#pragma unroll
            for (int a = 0; a < 4; ++a) xa[a] = xs4[(ty * 4 + a) * 9 + k4];
#pragma unroll
            for (int h = 0; h < 2; ++h) {       // j in 2 chunks: yc[4] live
                float4 yc[4];
#pragma unroll
                for (int cc = 0; cc < 4; ++cc)
                    yc[cc] = ys4[(tx + 16 * (4 * h + cc)) * 9 + k4];
#pragma unroll
                for (int a = 0; a < 4; ++a)
#pragma unroll
                    for (int cc = 0; cc < 4; ++cc)
                        acc[a][4 * h + cc] +=
                            xa[a].x * yc[cc].x + xa[a].y * yc[cc].y +
                            xa[a].z * yc[cc].z + xa[a].w * yc[cc].w;
            }
        }
    }
#pragma unroll
    for (int a = 0; a < 4; ++a) {
        const int gi = i0B + ty * 4 + a;
#pragma unroll
        for (int c = 0; c < 8; ++c)
            G[(size_t)gi * 32768 + jb + tx + 16 * c] = 40.f * acc[a][c];
    }
}

// ------------------------------------------------------------ iteration -----
// One fused Sinkhorn iteration. Block b owns columns [64b, 64b+64).
// Each thread caches a 16(row-strided) x 4(col) register tile of G.
// Last block (device-scope counter) combines all 512 row-partials -> su'.
__global__ __launch_bounds__(256) void sink_step(
    const float* __restrict__ G, float* __restrict__ su,
    float* __restrict__ W, float* __restrict__ pmT, float* __restrict__ psT,
    int* __restrict__ counter, const int* __restrict__ active, int gated)
{
    if (gated && active[0] == 0) return;
    __shared__ float su_lds[256];
    __shared__ float comb[1024];
    __shared__ float Mlds[64];
    __shared__ float Wlds[64];
    __shared__ float m_arr[256 * 17];
    __shared__ float s_arr[256 * 17];
    __shared__ int lastf;

    const int t  = threadIdx.x;
    const int b  = blockIdx.x;
    const int j0 = b << 6;
    const int jq = t & 15;       // column quad 0..15 (4 cols each)
    const int is = t >> 4;       // row subset 0..15 (rows is+16k)

    su_lds[t] = su[t];
    __syncthreads();

    const float4* G4 = (const float4*)G;
    float4 tile[16];
    float  sur[16];
#pragma unroll
    for (int k = 0; k < 16; ++k) {
        int i = is + (k << 4);
        tile[k] = G4[i * 8192 + (j0 >> 2) + jq];
        sur[k]  = su_lds[i];
    }

    // ---- phase C: column logsumexp over i (exact two-pass from registers)
    float m0 = -INFINITY, m1 = -INFINITY, m2 = -INFINITY, m3 = -INFINITY;
#pragma unroll
    for (int k = 0; k < 16; ++k) {
        m0 = fmaxf(m0, tile[k].x + sur[k]);
        m1 = fmaxf(m1, tile[k].y + sur[k]);
        m2 = fmaxf(m2, tile[k].z + sur[k]);
        m3 = fmaxf(m3, tile[k].w + sur[k]);
    }
    ((float4*)comb)[(is << 4) + jq] = make_float4(m0, m1, m2, m3);
    __syncthreads();
    if (t < 64) {
        float m = -INFINITY;
#pragma unroll
        for (int s = 0; s < 16; ++s) m = fmaxf(m, comb[(s << 6) + t]);
        Mlds[t] = m;
    }
    __syncthreads();
    float4 Mq = make_float4(Mlds[4 * jq + 0], Mlds[4 * jq + 1],
                            Mlds[4 * jq + 2], Mlds[4 * jq + 3]);
    float s0 = 0.f, s1 = 0.f, s2 = 0.f, s3 = 0.f;
#pragma unroll
    for (int k = 0; k < 16; ++k) {
        s0 += __expf(tile[k].x + sur[k] - Mq.x);
        s1 += __expf(tile[k].y + sur[k] - Mq.y);
        s2 += __expf(tile[k].z + sur[k] - Mq.z);
        s3 += __expf(tile[k].w + sur[k] - Mq.w);
    }
    ((float4*)comb)[(is << 4) + jq] = make_float4(s0, s1, s2, s3);
    __syncthreads();
    if (t < 64) {
        float ssum = 0.f;
#pragma unroll
        for (int s = 0; s < 16; ++s) ssum += comb[(s << 6) + t];
        float Wj = LOG_B - (Mlds[t] + __logf(ssum));
        Wlds[t] = Wj;
        W[j0 + t] = Wj;
    }
    __syncthreads();
    float4 Wq = make_float4(Wlds[4 * jq + 0], Wlds[4 * jq + 1],
                            Wlds[4 * jq + 2], Wlds[4 * jq + 3]);

    // ---- phase R: per-row partial lse over this block's 64 columns
#pragma unroll
    for (int k = 0; k < 16; ++k) {
        float a0 = tile[k].x + Wq.x;
        float a1 = tile[k].y + Wq.y;
        float a2 = tile[k].z + Wq.z;
        float a3 = tile[k].w + Wq.w;
        float m = fmaxf(fmaxf(a0, a1), fmaxf(a2, a3));
        float s = __expf(a0 - m) + __expf(a1 - m) + __expf(a2 - m) + __expf(a3 - m);
        int i = is + (k << 4);
        m_arr[i * 17 + jq] = m;   // stride 17: 2-way banks only (free, m136)
        s_arr[i * 17 + jq] = s;
    }
    __syncthreads();
    {   // thread t combines the 16 column-quad partials of row t
        float m = -INFINITY, s = 0.f;
#pragma unroll
        for (int p = 0; p < 16; ++p) {
            float pm = m_arr[t * 17 + p];
            float ps = s_arr[t * 17 + p];
            float nm = fmaxf(m, pm);
            s = s * __expf(m - nm) + ps * __expf(pm - nm);
            m = nm;
        }
        pmT[(t << 9) + b] = m;    // [row][block] layout: combine streams rows
        psT[(t << 9) + b] = s;
    }

    // ---- last-block combine (threadfence reduction, device scope)
    __threadfence();                       // release: partials -> device scope
    if (t == 0) lastf = (atomicAdd(counter, 1) == 511);
    __syncthreads();
    if (!lastf) return;
    __threadfence();                       // acquire: invalidate stale caches

    {   // thread t: row t, 512 partials, 4 interleaved lse chains for ILP
        const float* pm = pmT + (t << 9);
        const float* ps = psT + (t << 9);
        float cm[4] = {-INFINITY, -INFINITY, -INFINITY, -INFINITY};
        float cs[4] = {0.f, 0.f, 0.f, 0.f};
        for (int p = 0; p < 512; p += 4) {
#pragma unroll
            for (int c = 0; c < 4; ++c) {
                float pmv = pm[p + c], psv = ps[p + c];
                float nm = fmaxf(cm[c], pmv);
                cs[c] = cs[c] * __expf(cm[c] - nm) + psv * __expf(pmv - nm);
                cm[c] = nm;
            }
        }
        float m = cm[0], s = cs[0];
#pragma unroll
        for (int c = 1; c < 4; ++c) {
            float nm = fmaxf(m, cm[c]);
            s = s * __expf(m - nm) + cs[c] * __expf(cm[c] - nm);
            m = nm;
        }
        su[t] = LOG_A - (m + __logf(s));
    }
}

// --------------------------------------------- absorb-step column error -----
// col[j] = exp(lse_i(G+su') + W[j]);  err_col = max_j |col - b|.
__global__ __launch_bounds__(256) void sink_colerr(
    const float* __restrict__ G, const float* __restrict__ su,
    const float* __restrict__ W, unsigned* __restrict__ colerr, int slot,
    const int* __restrict__ active, int gated)
{
    if (gated && active[0] == 0) return;
    __shared__ float su_lds[256];
    __shared__ float comb[1024];
    __shared__ float Mlds[64];

    const int t  = threadIdx.x;
    const int b  = blockIdx.x;
    const int j0 = b << 6;
    const int jq = t & 15;
    const int is = t >> 4;

    su_lds[t] = su[t];
    __syncthreads();

    const float4* G4 = (const float4*)G;
    float4 tile[16];
    float  sur[16];
#pragma unroll
    for (int k = 0; k < 16; ++k) {
        int i = is + (k << 4);
        tile[k] = G4[i * 8192 + (j0 >> 2) + jq];
        sur[k]  = su_lds[i];
    }
    float m0 = -INFINITY, m1 = -INFINITY, m2 = -INFINITY, m3 = -INFINITY;
#pragma unroll
    for (int k = 0; k < 16; ++k) {
        m0 = fmaxf(m0, tile[k].x + sur[k]);
        m1 = fmaxf(m1, tile[k].y + sur[k]);
        m2 = fmaxf(m2, tile[k].z + sur[k]);
        m3 = fmaxf(m3, tile[k].w + sur[k]);
    }
    ((float4*)comb)[(is << 4) + jq] = make_float4(m0, m1, m2, m3);
    __syncthreads();
    if (t < 64) {
        float m = -INFINITY;
#pragma unroll
        for (int s = 0; s < 16; ++s) m = fmaxf(m, comb[(s << 6) + t]);
        Mlds[t] = m;
    }
    __syncthreads();
    float4 Mq = make_float4(Mlds[4 * jq + 0], Mlds[4 * jq + 1],
                            Mlds[4 * jq + 2], Mlds[4 * jq + 3]);
    float s0 = 0.f, s1 = 0.f, s2 = 0.f, s3 = 0.f;
#pragma unroll
    for (int k = 0; k < 16; ++k) {
        s0 += __expf(tile[k].x + sur[k] - Mq.x);
        s1 += __expf(tile[k].y + sur[k] - Mq.y);
        s2 += __expf(tile[k].z + sur[k] - Mq.z);
        s3 += __expf(tile[k].w + sur[k] - Mq.w);
    }
    ((float4*)comb)[(is << 4) + jq] = make_float4(s0, s1, s2, s3);
    __syncthreads();
    if (t < 64) {
        float ssum = 0.f;
#pragma unroll
        for (int s = 0; s < 16; ++s) ssum += comb[(s << 6) + t];
        float Aj  = Mlds[t] + __logf(ssum);
        float col = __expf(Aj + W[j0 + t]);
        float d   = fabsf(col - BVAL);
        for (int off = 32; off; off >>= 1) d = fmaxf(d, __shfl_down(d, off));
        if (t == 0) atomicMax(colerr + slot, __float_as_uint(d));  // d >= 0
    }
}

__global__ void sink_check(const unsigned* __restrict__ colerr, int slot,
                           int* __restrict__ active)
{
    if (threadIdx.x == 0)
        active[0] = (__uint_as_float(colerr[slot]) > 0.005f) ? 1 : 0;
}

// ------------------------------------------------------------- finalize -----
__global__ __launch_bounds__(256) void finalize_k(
    const float* __restrict__ G, const float* __restrict__ su,
    const float* __restrict__ W, const float* __restrict__ nx,
    const float* __restrict__ ny, float* __restrict__ out)
{
    __shared__ float su_lds[256], nx_lds[256];
    __shared__ float red[4];
    const int t = threadIdx.x, b = blockIdx.x;
    const int j0 = b << 6;
    su_lds[t] = su[t];
    nx_lds[t] = nx[t];
    __syncthreads();
    const int jj = t & 63, ig = t >> 6;
    const int j = j0 + jj;
    const float Wj = W[j], nyj = ny[j];
    float acc = 0.f;
#pragma unroll 4
    for (int k = 0; k < 64; ++k) {
        int i = ig + (k << 2);
        float g = G[i * 32768 + j];
        float v = __expf(g + su_lds[i] + Wj);
        out[1 + (size_t)i * 32768 + j] = v;
        acc += v * (nx_lds[i] + nyj - 0.05f * g);
    }
    for (int off = 32; off; off >>= 1) acc += __shfl_down(acc, off);
    if ((t & 63) == 0) red[t >> 6] = acc;
    __syncthreads();
    if (t == 0) atomicAdd(out, red[0] + red[1] + red[2] + red[3]);
}

// ---------------------------------------------------------------- host ------
extern "C" void kernel_launch(void* const* d_in, const int* in_sizes, int n_in,
                              void* d_out, int out_size, void* d_ws, size_t ws_size,
                              hipStream_t stream)
{
    const float* x = (const float*)d_in[0];   // [256, 384]
    const float* y = (const float*)d_in[1];   // [32768, 384]
    float* out = (float*)d_out;               // [1 + 256*32768]

    float* ws   = (float*)d_ws;
    float* G    = ws;                 // 8388608
    float* Wv   = G + 8388608;        // 32768
    float* su   = Wv + 32768;         // 256
    float* nx   = su + 256;           // 256
    float* ny   = nx + 256;           // 32768
    float* pmT  = ny + 32768;         // 131072  [row][block]
    float* psT  = pmT + 131072;       // 131072
    unsigned* colerr = (unsigned*)(psT + 131072);  // 2
    int* active   = (int*)(colerr + 2);            // 1
    int* counters = active + 1;                    // 128 (one per iteration)

    init_k<<<8257, 256, 0, stream>>>(x, y, nx, ny, su, colerr, active, counters, out);
    gemm_k<<<dim3(256, 4), 256, 0, stream>>>(x, y, G);

    // iteration 1 (always runs) + absorb error check
    sink_step<<<512, 256, 0, stream>>>(G, su, Wv, pmT, psT, counters + 0, active, 0);
    sink_colerr<<<512, 256, 0, stream>>>(G, su, Wv, colerr, 0, active, 0);
    sink_check<<<1, 64, 0, stream>>>(colerr, 0, active);

    for (int tt = 2; tt <= 100; ++tt) {
        sink_step<<<512, 256, 0, stream>>>(G, su, Wv, pmT, psT, counters + tt - 1, active, 1);
        if (tt == 51) {   // absorb at cpt_n=51: error check gates the rest
            sink_colerr<<<512, 256, 0, stream>>>(G, su, Wv, colerr, 1, active, 1);
            sink_check<<<1, 64, 0, stream>>>(colerr, 1, active);
        }
    }

    finalize_k<<<512, 256, 0, stream>>>(G, su, Wv, nx, ny, out);
}

// Round 5
// 432.032 us; speedup vs baseline: 3.9692x; 1.3878x over previous
//
#include <hip/hip_runtime.h>
#include <math.h>

// ---------------------------------------------------------------------------
// Sinkhorn ETP (FASTopic) on MI355X.
// n=256 topics, m=32768 words, D=384.
//
// State reduction (derived from the reference):
//   log_K0[i,j] = G[i,j] + su0[i] + sv0[j],  G = 40 * x@y^T
//   Per iteration:  L1[j] = lse_i(G+su);  W[j] = log_b - L1[j]
//                   L2[i] = lse_j(G+W);   su'[i] = log_a - L2[i]
//   Final: transp[i,j] = exp(G+su[i]+W[j]); M = nx[i]+ny[j]-0.05*G;
//          loss = sum(transp*M)
//
// GEMM: MFMA bf16 with exact 3-way truncation split (x=x1+x2+x3, y=y1+y2+y3,
// terms 11,12,21,22,13,31 kept -> G rel err ~1e-7 from split, ~1e-6 from fp32
// accumulation; dropped terms <= 2^-27). fp32-vector gemm history: best 235us
// (latency-bound at 2 blk/CU; LDS floor ~93us) -> MFMA floor ~19us.
// ---------------------------------------------------------------------------

#define N_TOPIC 256
#define N_WORD  32768

static constexpr float LOG_A = -5.545177444479562f;    // log(1/256 + 1e-30)
static constexpr float LOG_B = -10.397207708399179f;   // log(1/32768 + 1e-30)
static constexpr float BVAL  = 3.0517578125e-05f;      // 1/32768

typedef float f32x4 __attribute__((ext_vector_type(4)));
typedef short bf16x8 __attribute__((ext_vector_type(8)));

// ---------------------------------------------------------------- init ------
__global__ __launch_bounds__(256) void init_k(
    const float* __restrict__ x, const float* __restrict__ y,
    float* __restrict__ nx, float* __restrict__ ny, float* __restrict__ su,
    unsigned* __restrict__ colerr, int* __restrict__ active,
    int* __restrict__ counters, float* __restrict__ out)
{
    const int b = blockIdx.x, t = threadIdx.x;
    const int w = t >> 6, l = t & 63;
    if (b < 8192) {                       // ||y_j||^2, 4 rows/block (wave per row)
        const int r = (b << 2) + w;
        const float4* y4 = (const float4*)y;
        float4 v = y4[r * 96 + l];
        float s = v.x * v.x + v.y * v.y + v.z * v.z + v.w * v.w;
        if (l < 32) {
            float4 u = y4[r * 96 + 64 + l];
            s += u.x * u.x + u.y * u.y + u.z * u.z + u.w * u.w;
        }
        for (int off = 32; off; off >>= 1) s += __shfl_down(s, off);
        if (l == 0) ny[r] = s;
    } else if (b < 8256) {                // ||x_i||^2 and su0 = -20*nx
        const int r = ((b - 8192) << 2) + w;
        const float4* x4 = (const float4*)x;
        float4 v = x4[r * 96 + l];
        float s = v.x * v.x + v.y * v.y + v.z * v.z + v.w * v.w;
        if (l < 32) {
            float4 u = x4[r * 96 + 64 + l];
            s += u.x * u.x + u.y * u.y + u.z * u.z + u.w * u.w;
        }
        for (int off = 32; off; off >>= 1) s += __shfl_down(s, off);
        if (l == 0) { nx[r] = s; su[r] = -20.f * s; }
    } else {
        if (t < 128) counters[t] = 0;     // per-iteration last-block counters
        if (t == 0) { colerr[0] = 0u; colerr[1] = 0u; active[0] = 1; out[0] = 0.f; }
    }
}

// ---------------------------------------------------------------- gemm ------
// Exact 3-way bf16 truncation split: v = b0 + b1 + b2 (+ r3, |r3|<=2^-27|v|).
// Each level's value is exactly bf16-representable (upper-16-bit mask).
static __device__ __forceinline__ void split3(float v, ushort& h0, ushort& h1, ushort& h2)
{
    unsigned u0 = __float_as_uint(v);
    h0 = (ushort)(u0 >> 16);
    float r1 = v - __uint_as_float(u0 & 0xFFFF0000u);
    unsigned u1 = __float_as_uint(r1);
    h1 = (ushort)(u1 >> 16);
    float r2 = r1 - __uint_as_float(u1 & 0xFFFF0000u);
    h2 = (ushort)(__float_as_uint(r2) >> 16);
}

// Block tile 128i x 128j, K-chunks of 32, grid (256 jb, 2 ib) = 512 blocks.
// Wave w owns i-strip [32w, 32w+32) (2 mi-tiles) x all 128 j (8 nj-tiles).
// Frag layouts (m89/m91-verified): A[m=lane&15][k=quad*8+e] from x rows;
// y is [j][k] row-major = B^T, so B-frags use the identical row pattern.
// C/D: col=lane&15, row=quad*4+reg.
// LDS rows padded to 40 bf16 (80 B): 16B-aligned b128 reads, ~2-way banks.
__global__ __launch_bounds__(256, 1) void gemm_k(
    const float* __restrict__ x, const float* __restrict__ y, float* __restrict__ G)
{
    __shared__ __align__(16) ushort xs0[5120], xs1[5120], xs2[5120];
    __shared__ __align__(16) ushort ys0[5120], ys1[5120], ys2[5120];

    const int t   = threadIdx.x;
    const int jb  = blockIdx.x << 7;   // 128-col slab
    const int ib  = blockIdx.y << 7;   // 128-row slab
    const int w   = t >> 6;            // wave 0..3
    const int ln  = t & 63;
    const int q   = ln >> 4;           // quad 0..3
    const int l15 = ln & 15;

    const float4* x4 = (const float4*)x;
    const float4* y4 = (const float4*)y;

    f32x4 acc[2][8];
#pragma unroll
    for (int mi = 0; mi < 2; ++mi)
#pragma unroll
        for (int nj = 0; nj < 8; ++nj) acc[mi][nj] = (f32x4){0.f, 0.f, 0.f, 0.f};

    for (int kc = 0; kc < 12; ++kc) {
        __syncthreads();
        // stage x & y fp32 -> 3-level bf16 LDS tiles (128 rows x 32 k)
#pragma unroll
        for (int p = 0; p < 4; ++p) {
            const int f  = (t << 2) + p;       // 0..1023 float4 slots
            const int r  = f >> 3, c4 = f & 7; // row, k-quad
            const int o  = r * 40 + (c4 << 2);
            float4 vx = x4[(ib + r) * 96 + (kc << 3) + c4];
            ushort a0,a1,a2,b0,b1,b2,c0,c1,c2,d0,d1,d2;
            split3(vx.x, a0,a1,a2); split3(vx.y, b0,b1,b2);
            split3(vx.z, c0,c1,c2); split3(vx.w, d0,d1,d2);
            *(ushort4*)&xs0[o] = make_ushort4(a0,b0,c0,d0);
            *(ushort4*)&xs1[o] = make_ushort4(a1,b1,c1,d1);
            *(ushort4*)&xs2[o] = make_ushort4(a2,b2,c2,d2);
            float4 vy = y4[(jb + r) * 96 + (kc << 3) + c4];
            split3(vy.x, a0,a1,a2); split3(vy.y, b0,b1,b2);
            split3(vy.z, c0,c1,c2); split3(vy.w, d0,d1,d2);
            *(ushort4*)&ys0[o] = make_ushort4(a0,b0,c0,d0);
            *(ushort4*)&ys1[o] = make_ushort4(a1,b1,c1,d1);
            *(ushort4*)&ys2[o] = make_ushort4(a2,b2,c2,d2);
        }
        __syncthreads();

        // A fragments for this wave's 2 mi-tiles, 3 levels
        bf16x8 A[3][2];
#pragma unroll
        for (int mi = 0; mi < 2; ++mi) {
            const int off = ((w << 5) + (mi << 4) + l15) * 40 + (q << 3);
            A[0][mi] = *(const bf16x8*)&xs0[off];
            A[1][mi] = *(const bf16x8*)&xs1[off];
            A[2][mi] = *(const bf16x8*)&xs2[off];
        }
#pragma unroll
        for (int nj = 0; nj < 8; ++nj) {
            const int off = ((nj << 4) + l15) * 40 + (q << 3);
            bf16x8 B0 = *(const bf16x8*)&ys0[off];
            bf16x8 B1 = *(const bf16x8*)&ys1[off];
            bf16x8 B2 = *(const bf16x8*)&ys2[off];
#pragma unroll
            for (int mi = 0; mi < 2; ++mi) {
                f32x4 c = acc[mi][nj];
                c = __builtin_amdgcn_mfma_f32_16x16x32_bf16(A[0][mi], B0, c, 0, 0, 0);
                c = __builtin_amdgcn_mfma_f32_16x16x32_bf16(A[0][mi], B1, c, 0, 0, 0);
                c = __builtin_amdgcn_mfma_f32_16x16x32_bf16(A[1][mi], B0, c, 0, 0, 0);
                c = __builtin_amdgcn_mfma_f32_16x16x32_bf16(A[1][mi], B1, c, 0, 0, 0);
                c = __builtin_amdgcn_mfma_f32_16x16x32_bf16(A[0][mi], B2, c, 0, 0, 0);
                c = __builtin_amdgcn_mfma_f32_16x16x32_bf16(A[2][mi], B0, c, 0, 0, 0);
                acc[mi][nj] = c;
            }
        }
    }
    // epilogue: C/D row = quad*4+reg, col = lane&15
#pragma unroll
    for (int mi = 0; mi < 2; ++mi) {
        const int gi0 = ib + (w << 5) + (mi << 4) + (q << 2);
#pragma unroll
        for (int nj = 0; nj < 8; ++nj) {
            const int gj = jb + (nj << 4) + l15;
#pragma unroll
            for (int r = 0; r < 4; ++r)
                G[(size_t)(gi0 + r) * 32768 + gj] = 40.f * acc[mi][nj][r];
        }
    }
}

// ------------------------------------------------------------ iteration -----
// One fused Sinkhorn iteration. Block b owns columns [64b, 64b+64).
// Each thread caches a 16(row-strided) x 4(col) register tile of G.
// Last block (device-scope counter) combines all 512 row-partials -> su'.
__global__ __launch_bounds__(256) void sink_step(
    const float* __restrict__ G, float* __restrict__ su,
    float* __restrict__ W, float* __restrict__ pmT, float* __restrict__ psT,
    int* __restrict__ counter, const int* __restrict__ active, int gated)
{
    if (gated && active[0] == 0) return;
    __shared__ float su_lds[256];
    __shared__ float comb[1024];
    __shared__ float Mlds[64];
    __shared__ float Wlds[64];
    __shared__ float m_arr[256 * 17];
    __shared__ float s_arr[256 * 17];
    __shared__ int lastf;

    const int t  = threadIdx.x;
    const int b  = blockIdx.x;
    const int j0 = b << 6;
    const int jq = t & 15;       // column quad 0..15 (4 cols each)
    const int is = t >> 4;       // row subset 0..15 (rows is+16k)

    su_lds[t] = su[t];
    __syncthreads();

    const float4* G4 = (const float4*)G;
    float4 tile[16];
    float  sur[16];
#pragma unroll
    for (int k = 0; k < 16; ++k) {
        int i = is + (k << 4);
        tile[k] = G4[i * 8192 + (j0 >> 2) + jq];
        sur[k]  = su_lds[i];
    }

    // ---- phase C: column logsumexp over i (exact two-pass from registers)
    float m0 = -INFINITY, m1 = -INFINITY, m2 = -INFINITY, m3 = -INFINITY;
#pragma unroll
    for (int k = 0; k < 16; ++k) {
        m0 = fmaxf(m0, tile[k].x + sur[k]);
        m1 = fmaxf(m1, tile[k].y + sur[k]);
        m2 = fmaxf(m2, tile[k].z + sur[k]);
        m3 = fmaxf(m3, tile[k].w + sur[k]);
    }
    ((float4*)comb)[(is << 4) + jq] = make_float4(m0, m1, m2, m3);
    __syncthreads();
    if (t < 64) {
        float m = -INFINITY;
#pragma unroll
        for (int s = 0; s < 16; ++s) m = fmaxf(m, comb[(s << 6) + t]);
        Mlds[t] = m;
    }
    __syncthreads();
    float4 Mq = make_float4(Mlds[4 * jq + 0], Mlds[4 * jq + 1],
                            Mlds[4 * jq + 2], Mlds[4 * jq + 3]);
    float s0 = 0.f, s1 = 0.f, s2 = 0.f, s3 = 0.f;
#pragma unroll
    for (int k = 0; k < 16; ++k) {
        s0 += __expf(tile[k].x + sur[k] - Mq.x);
        s1 += __expf(tile[k].y + sur[k] - Mq.y);
        s2 += __expf(tile[k].z + sur[k] - Mq.z);
        s3 += __expf(tile[k].w + sur[k] - Mq.w);
    }
    ((float4*)comb)[(is << 4) + jq] = make_float4(s0, s1, s2, s3);
    __syncthreads();
    if (t < 64) {
        float ssum = 0.f;
#pragma unroll
        for (int s = 0; s < 16; ++s) ssum += comb[(s << 6) + t];
        float Wj = LOG_B - (Mlds[t] + __logf(ssum));
        Wlds[t] = Wj;
        W[j0 + t] = Wj;
    }
    __syncthreads();
    float4 Wq = make_float4(Wlds[4 * jq + 0], Wlds[4 * jq + 1],
                            Wlds[4 * jq + 2], Wlds[4 * jq + 3]);

    // ---- phase R: per-row partial lse over this block's 64 columns
#pragma unroll
    for (int k = 0; k < 16; ++k) {
        float a0 = tile[k].x + Wq.x;
        float a1 = tile[k].y + Wq.y;
        float a2 = tile[k].z + Wq.z;
        float a3 = tile[k].w + Wq.w;
        float m = fmaxf(fmaxf(a0, a1), fmaxf(a2, a3));
        float s = __expf(a0 - m) + __expf(a1 - m) + __expf(a2 - m) + __expf(a3 - m);
        int i = is + (k << 4);
        m_arr[i * 17 + jq] = m;   // stride 17: 2-way banks only (free, m136)
        s_arr[i * 17 + jq] = s;
    }
    __syncthreads();
    {   // thread t combines the 16 column-quad partials of row t
        float m = -INFINITY, s = 0.f;
#pragma unroll
        for (int p = 0; p < 16; ++p) {
            float pm = m_arr[t * 17 + p];
            float ps = s_arr[t * 17 + p];
            float nm = fmaxf(m, pm);
            s = s * __expf(m - nm) + ps * __expf(pm - nm);
            m = nm;
        }
        pmT[(t << 9) + b] = m;    // [row][block] layout: combine streams rows
        psT[(t << 9) + b] = s;
    }

    // ---- last-block combine (threadfence reduction, device scope)
    __threadfence();                       // release: partials -> device scope
    if (t == 0) lastf = (atomicAdd(counter, 1) == 511);
    __syncthreads();
    if (!lastf) return;
    __threadfence();                       // acquire: invalidate stale caches

    {   // thread t: row t, 512 partials, 4 interleaved lse chains for ILP
        const float* pm = pmT + (t << 9);
        const float* ps = psT + (t << 9);
        float cm[4] = {-INFINITY, -INFINITY, -INFINITY, -INFINITY};
        float cs[4] = {0.f, 0.f, 0.f, 0.f};
        for (int p = 0; p < 512; p += 4) {
#pragma unroll
            for (int c = 0; c < 4; ++c) {
                float pmv = pm[p + c], psv = ps[p + c];
                float nm = fmaxf(cm[c], pmv);
                cs[c] = cs[c] * __expf(cm[c] - nm) + psv * __expf(pmv - nm);
                cm[c] = nm;
            }
        }
        float m = cm[0], s = cs[0];
#pragma unroll
        for (int c = 1; c < 4; ++c) {
            float nm = fmaxf(m, cm[c]);
            s = s * __expf(m - nm) + cs[c] * __expf(cm[c] - nm);
            m = nm;
        }
        su[t] = LOG_A - (m + __logf(s));
    }
}

// --------------------------------------------- absorb-step column error -----
// col[j] = exp(lse_i(G+su') + W[j]);  err_col = max_j |col - b|.
__global__ __launch_bounds__(256) void sink_colerr(
    const float* __restrict__ G, const float* __restrict__ su,
    const float* __restrict__ W, unsigned* __restrict__ colerr, int slot,
    const int* __restrict__ active, int gated)
{
    if (gated && active[0] == 0) return;
    __shared__ float su_lds[256];
    __shared__ float comb[1024];
    __shared__ float Mlds[64];

    const int t  = threadIdx.x;
    const int b  = blockIdx.x;
    const int j0 = b << 6;
    const int jq = t & 15;
    const int is = t >> 4;

    su_lds[t] = su[t];
    __syncthreads();

    const float4* G4 = (const float4*)G;
    float4 tile[16];
    float  sur[16];
#pragma unroll
    for (int k = 0; k < 16; ++k) {
        int i = is + (k << 4);
        tile[k] = G4[i * 8192 + (j0 >> 2) + jq];
        sur[k]  = su_lds[i];
    }
    float m0 = -INFINITY, m1 = -INFINITY, m2 = -INFINITY, m3 = -INFINITY;
#pragma unroll
    for (int k = 0; k < 16; ++k) {
        m0 = fmaxf(m0, tile[k].x + sur[k]);
        m1 = fmaxf(m1, tile[k].y + sur[k]);
        m2 = fmaxf(m2, tile[k].z + sur[k]);
        m3 = fmaxf(m3, tile[k].w + sur[k]);
    }
    ((float4*)comb)[(is << 4) + jq] = make_float4(m0, m1, m2, m3);
    __syncthreads();
    if (t < 64) {
        float m = -INFINITY;
#pragma unroll
        for (int s = 0; s < 16; ++s) m = fmaxf(m, comb[(s << 6) + t]);
        Mlds[t] = m;
    }
    __syncthreads();
    float4 Mq = make_float4(Mlds[4 * jq + 0], Mlds[4 * jq + 1],
                            Mlds[4 * jq + 2], Mlds[4 * jq + 3]);
    float s0 = 0.f, s1 = 0.f, s2 = 0.f, s3 = 0.f;
#pragma unroll
    for (int k = 0; k < 16; ++k) {
        s0 += __expf(tile[k].x + sur[k] - Mq.x);
        s1 += __expf(tile[k].y + sur[k] - Mq.y);
        s2 += __expf(tile[k].z + sur[k] - Mq.z);
        s3 += __expf(tile[k].w + sur[k] - Mq.w);
    }
    ((float4*)comb)[(is << 4) + jq] = make_float4(s0, s1, s2, s3);
    __syncthreads();
    if (t < 64) {
        float ssum = 0.f;
#pragma unroll
        for (int s = 0; s < 16; ++s) ssum += comb[(s << 6) + t];
        float Aj  = Mlds[t] + __logf(ssum);
        float col = __expf(Aj + W[j0 + t]);
        float d   = fabsf(col - BVAL);
        for (int off = 32; off; off >>= 1) d = fmaxf(d, __shfl_down(d, off));
        if (t == 0) atomicMax(colerr + slot, __float_as_uint(d));  // d >= 0
    }
}

__global__ void sink_check(const unsigned* __restrict__ colerr, int slot,
                           int* __restrict__ active)
{
    if (threadIdx.x == 0)
        active[0] = (__uint_as_float(colerr[slot]) > 0.005f) ? 1 : 0;
}

// ------------------------------------------------------------- finalize -----
__global__ __launch_bounds__(256) void finalize_k(
    const float* __restrict__ G, const float* __restrict__ su,
    const float* __restrict__ W, const float* __restrict__ nx,
    const float* __restrict__ ny, float* __restrict__ out)
{
    __shared__ float su_lds[256], nx_lds[256];
    __shared__ float red[4];
    const int t = threadIdx.x, b = blockIdx.x;
    const int j0 = b << 6;
    su_lds[t] = su[t];
    nx_lds[t] = nx[t];
    __syncthreads();
    const int jj = t & 63, ig = t >> 6;
    const int j = j0 + jj;
    const float Wj = W[j], nyj = ny[j];
    float acc = 0.f;
#pragma unroll 4
    for (int k = 0; k < 64; ++k) {
        int i = ig + (k << 2);
        float g = G[i * 32768 + j];
        float v = __expf(g + su_lds[i] + Wj);
        out[1 + (size_t)i * 32768 + j] = v;
        acc += v * (nx_lds[i] + nyj - 0.05f * g);
    }
    for (int off = 32; off; off >>= 1) acc += __shfl_down(acc, off);
    if ((t & 63) == 0) red[t >> 6] = acc;
    __syncthreads();
    if (t == 0) atomicAdd(out, red[0] + red[1] + red[2] + red[3]);
}

// ---------------------------------------------------------------- host ------
extern "C" void kernel_launch(void* const* d_in, const int* in_sizes, int n_in,
                              void* d_out, int out_size, void* d_ws, size_t ws_size,
                              hipStream_t stream)
{
    const float* x = (const float*)d_in[0];   // [256, 384]
    const float* y = (const float*)d_in[1];   // [32768, 384]
    float* out = (float*)d_out;               // [1 + 256*32768]

    float* ws   = (float*)d_ws;
    float* G    = ws;                 // 8388608
    float* Wv   = G + 8388608;        // 32768
    float* su   = Wv + 32768;         // 256
    float* nx   = su + 256;           // 256
    float* ny   = nx + 256;           // 32768
    float* pmT  = ny + 32768;         // 131072  [row][block]
    float* psT  = pmT + 131072;       // 131072
    unsigned* colerr = (unsigned*)(psT + 131072);  // 2
    int* active   = (int*)(colerr + 2);            // 1
    int* counters = active + 1;                    // 128 (one per iteration)

    init_k<<<8257, 256, 0, stream>>>(x, y, nx, ny, su, colerr, active, counters, out);
    gemm_k<<<dim3(256, 2), 256, 0, stream>>>(x, y, G);

    // iteration 1 (always runs) + absorb error check
    sink_step<<<512, 256, 0, stream>>>(G, su, Wv, pmT, psT, counters + 0, active, 0);
    sink_colerr<<<512, 256, 0, stream>>>(G, su, Wv, colerr, 0, active, 0);
    sink_check<<<1, 64, 0, stream>>>(colerr, 0, active);

    for (int tt = 2; tt <= 100; ++tt) {
        sink_step<<<512, 256, 0, stream>>>(G, su, Wv, pmT, psT, counters + tt - 1, active, 1);
        if (tt == 51) {   // absorb at cpt_n=51: error check gates the rest
            sink_colerr<<<512, 256, 0, stream>>>(G, su, Wv, colerr, 1, active, 1);
            sink_check<<<1, 64, 0, stream>>>(colerr, 1, active);
        }
    }

    finalize_k<<<512, 256, 0, stream>>>(G, su, Wv, nx, ny, out);
}

// Round 6
// 394.837 us; speedup vs baseline: 4.3431x; 1.0942x over previous
//
#include <hip/hip_runtime.h>
#include <math.h>

// ---------------------------------------------------------------------------
// Sinkhorn ETP (FASTopic) on MI355X.
// n=256 topics, m=32768 words, D=384.
//
// State reduction (derived from the reference):
//   log_K0[i,j] = G[i,j] + su0[i] + sv0[j],  G = 40 * x@y^T
//   Per iteration:  L1[j] = lse_i(G+su);  W[j] = log_b - L1[j]
//                   L2[i] = lse_j(G+W);   su'[i] = log_a - L2[i]
//   Final: transp[i,j] = exp(G+su[i]+W[j]); M = nx[i]+ny[j]-0.05*G;
//          loss = sum(transp*M)
//
// GEMM: MFMA bf16 exact 3-way truncation split (R5: absmax 1.9e-6, works).
// R6: coalesced last-block combine (pm[b*256+row], was 64-way uncoalesced),
// direct su loads (-1 barrier), check folded into colerr, float4 finalize.
// ---------------------------------------------------------------------------

#define N_TOPIC 256
#define N_WORD  32768

static constexpr float LOG_A = -5.545177444479562f;    // log(1/256 + 1e-30)
static constexpr float LOG_B = -10.397207708399179f;   // log(1/32768 + 1e-30)
static constexpr float BVAL  = 3.0517578125e-05f;      // 1/32768

typedef float f32x4 __attribute__((ext_vector_type(4)));
typedef short bf16x8 __attribute__((ext_vector_type(8)));

// ---------------------------------------------------------------- init ------
__global__ __launch_bounds__(256) void init_k(
    const float* __restrict__ x, const float* __restrict__ y,
    float* __restrict__ nx, float* __restrict__ ny, float* __restrict__ su,
    unsigned* __restrict__ colerr, int* __restrict__ active,
    int* __restrict__ counters, float* __restrict__ out)
{
    const int b = blockIdx.x, t = threadIdx.x;
    const int w = t >> 6, l = t & 63;
    if (b < 8192) {                       // ||y_j||^2, 4 rows/block (wave per row)
        const int r = (b << 2) + w;
        const float4* y4 = (const float4*)y;
        float4 v = y4[r * 96 + l];
        float s = v.x * v.x + v.y * v.y + v.z * v.z + v.w * v.w;
        if (l < 32) {
            float4 u = y4[r * 96 + 64 + l];
            s += u.x * u.x + u.y * u.y + u.z * u.z + u.w * u.w;
        }
        for (int off = 32; off; off >>= 1) s += __shfl_down(s, off);
        if (l == 0) ny[r] = s;
    } else if (b < 8256) {                // ||x_i||^2 and su0 = -20*nx
        const int r = ((b - 8192) << 2) + w;
        const float4* x4 = (const float4*)x;
        float4 v = x4[r * 96 + l];
        float s = v.x * v.x + v.y * v.y + v.z * v.z + v.w * v.w;
        if (l < 32) {
            float4 u = x4[r * 96 + 64 + l];
            s += u.x * u.x + u.y * u.y + u.z * u.z + u.w * u.w;
        }
        for (int off = 32; off; off >>= 1) s += __shfl_down(s, off);
        if (l == 0) { nx[r] = s; su[r] = -20.f * s; }
    } else {
        if (t < 128) counters[t] = 0;     // last-block counters (iters + colerr)
        if (t == 0) { colerr[0] = 0u; colerr[1] = 0u; active[0] = 1; out[0] = 0.f; }
    }
}

// ---------------------------------------------------------------- gemm ------
// Exact 3-way bf16 truncation split: v = b0 + b1 + b2 (+ r3, |r3|<=2^-27|v|).
static __device__ __forceinline__ void split3(float v, ushort& h0, ushort& h1, ushort& h2)
{
    unsigned u0 = __float_as_uint(v);
    h0 = (ushort)(u0 >> 16);
    float r1 = v - __uint_as_float(u0 & 0xFFFF0000u);
    unsigned u1 = __float_as_uint(r1);
    h1 = (ushort)(u1 >> 16);
    float r2 = r1 - __uint_as_float(u1 & 0xFFFF0000u);
    h2 = (ushort)(__float_as_uint(r2) >> 16);
}

// Block tile 128i x 128j, K-chunks of 32, grid (256 jb, 2 ib) = 512 blocks.
// Frag layouts (m89/m91-verified); y is [j][k] row-major = B^T identical frag.
__global__ __launch_bounds__(256, 1) void gemm_k(
    const float* __restrict__ x, const float* __restrict__ y, float* __restrict__ G)
{
    __shared__ __align__(16) ushort xs0[5120], xs1[5120], xs2[5120];
    __shared__ __align__(16) ushort ys0[5120], ys1[5120], ys2[5120];

    const int t   = threadIdx.x;
    const int jb  = blockIdx.x << 7;   // 128-col slab
    const int ib  = blockIdx.y << 7;   // 128-row slab
    const int w   = t >> 6;            // wave 0..3
    const int ln  = t & 63;
    const int q   = ln >> 4;           // quad 0..3
    const int l15 = ln & 15;

    const float4* x4 = (const float4*)x;
    const float4* y4 = (const float4*)y;

    f32x4 acc[2][8];
#pragma unroll
    for (int mi = 0; mi < 2; ++mi)
#pragma unroll
        for (int nj = 0; nj < 8; ++nj) acc[mi][nj] = (f32x4){0.f, 0.f, 0.f, 0.f};

    for (int kc = 0; kc < 12; ++kc) {
        __syncthreads();
#pragma unroll
        for (int p = 0; p < 4; ++p) {
            const int f  = (t << 2) + p;       // 0..1023 float4 slots
            const int r  = f >> 3, c4 = f & 7; // row, k-quad
            const int o  = r * 40 + (c4 << 2);
            float4 vx = x4[(ib + r) * 96 + (kc << 3) + c4];
            ushort a0,a1,a2,b0,b1,b2,c0,c1,c2,d0,d1,d2;
            split3(vx.x, a0,a1,a2); split3(vx.y, b0,b1,b2);
            split3(vx.z, c0,c1,c2); split3(vx.w, d0,d1,d2);
            *(ushort4*)&xs0[o] = make_ushort4(a0,b0,c0,d0);
            *(ushort4*)&xs1[o] = make_ushort4(a1,b1,c1,d1);
            *(ushort4*)&xs2[o] = make_ushort4(a2,b2,c2,d2);
            float4 vy = y4[(jb + r) * 96 + (kc << 3) + c4];
            split3(vy.x, a0,a1,a2); split3(vy.y, b0,b1,b2);
            split3(vy.z, c0,c1,c2); split3(vy.w, d0,d1,d2);
            *(ushort4*)&ys0[o] = make_ushort4(a0,b0,c0,d0);
            *(ushort4*)&ys1[o] = make_ushort4(a1,b1,c1,d1);
            *(ushort4*)&ys2[o] = make_ushort4(a2,b2,c2,d2);
        }
        __syncthreads();

        bf16x8 A[3][2];
#pragma unroll
        for (int mi = 0; mi < 2; ++mi) {
            const int off = ((w << 5) + (mi << 4) + l15) * 40 + (q << 3);
            A[0][mi] = *(const bf16x8*)&xs0[off];
            A[1][mi] = *(const bf16x8*)&xs1[off];
            A[2][mi] = *(const bf16x8*)&xs2[off];
        }
#pragma unroll
        for (int nj = 0; nj < 8; ++nj) {
            const int off = ((nj << 4) + l15) * 40 + (q << 3);
            bf16x8 B0 = *(const bf16x8*)&ys0[off];
            bf16x8 B1 = *(const bf16x8*)&ys1[off];
            bf16x8 B2 = *(const bf16x8*)&ys2[off];
#pragma unroll
            for (int mi = 0; mi < 2; ++mi) {
                f32x4 c = acc[mi][nj];
                c = __builtin_amdgcn_mfma_f32_16x16x32_bf16(A[0][mi], B0, c, 0, 0, 0);
                c = __builtin_amdgcn_mfma_f32_16x16x32_bf16(A[0][mi], B1, c, 0, 0, 0);
                c = __builtin_amdgcn_mfma_f32_16x16x32_bf16(A[1][mi], B0, c, 0, 0, 0);
                c = __builtin_amdgcn_mfma_f32_16x16x32_bf16(A[1][mi], B1, c, 0, 0, 0);
                c = __builtin_amdgcn_mfma_f32_16x16x32_bf16(A[0][mi], B2, c, 0, 0, 0);
                c = __builtin_amdgcn_mfma_f32_16x16x32_bf16(A[2][mi], B0, c, 0, 0, 0);
                acc[mi][nj] = c;
            }
        }
    }
#pragma unroll
    for (int mi = 0; mi < 2; ++mi) {
        const int gi0 = ib + (w << 5) + (mi << 4) + (q << 2);
#pragma unroll
        for (int nj = 0; nj < 8; ++nj) {
            const int gj = jb + (nj << 4) + l15;
#pragma unroll
            for (int r = 0; r < 4; ++r)
                G[(size_t)(gi0 + r) * 32768 + gj] = 40.f * acc[mi][nj][r];
        }
    }
}

// ------------------------------------------------------------ iteration -----
// One fused Sinkhorn iteration. Block b owns columns [64b, 64b+64).
// Partials layout pm[b*256+row]: contiguous per-block write AND coalesced
// last-block read (R5 had row-major -> 64-way uncoalesced combine tail).
__global__ __launch_bounds__(256) void sink_step(
    const float* __restrict__ G, float* __restrict__ su,
    float* __restrict__ W, float* __restrict__ pm, float* __restrict__ ps,
    int* __restrict__ counter, const int* __restrict__ active, int gated)
{
    if (gated && active[0] == 0) return;
    __shared__ float comb[1024];
    __shared__ float Mlds[64];
    __shared__ float Wlds[64];
    __shared__ float m_arr[256 * 17];
    __shared__ float s_arr[256 * 17];
    __shared__ int lastf;

    const int t  = threadIdx.x;
    const int b  = blockIdx.x;
    const int j0 = b << 6;
    const int jq = t & 15;       // column quad 0..15 (4 cols each)
    const int is = t >> 4;       // row subset 0..15 (rows is+16k)

    const float4* G4 = (const float4*)G;
    float4 tile[16];
    float  sur[16];
#pragma unroll
    for (int k = 0; k < 16; ++k) {
        int i = is + (k << 4);
        tile[k] = G4[i * 8192 + (j0 >> 2) + jq];
        sur[k]  = su[i];          // broadcast loads, L1/L2-hot (no barrier)
    }

    // ---- phase C: column logsumexp over i (exact two-pass from registers)
    float m0 = -INFINITY, m1 = -INFINITY, m2 = -INFINITY, m3 = -INFINITY;
#pragma unroll
    for (int k = 0; k < 16; ++k) {
        m0 = fmaxf(m0, tile[k].x + sur[k]);
        m1 = fmaxf(m1, tile[k].y + sur[k]);
        m2 = fmaxf(m2, tile[k].z + sur[k]);
        m3 = fmaxf(m3, tile[k].w + sur[k]);
    }
    ((float4*)comb)[(is << 4) + jq] = make_float4(m0, m1, m2, m3);
    __syncthreads();
    if (t < 64) {
        float m = -INFINITY;
#pragma unroll
        for (int s = 0; s < 16; ++s) m = fmaxf(m, comb[(s << 6) + t]);
        Mlds[t] = m;
    }
    __syncthreads();
    float4 Mq = make_float4(Mlds[4 * jq + 0], Mlds[4 * jq + 1],
                            Mlds[4 * jq + 2], Mlds[4 * jq + 3]);
    float s0 = 0.f, s1 = 0.f, s2 = 0.f, s3 = 0.f;
#pragma unroll
    for (int k = 0; k < 16; ++k) {
        s0 += __expf(tile[k].x + sur[k] - Mq.x);
        s1 += __expf(tile[k].y + sur[k] - Mq.y);
        s2 += __expf(tile[k].z + sur[k] - Mq.z);
        s3 += __expf(tile[k].w + sur[k] - Mq.w);
    }
    ((float4*)comb)[(is << 4) + jq] = make_float4(s0, s1, s2, s3);
    __syncthreads();
    if (t < 64) {
        float ssum = 0.f;
#pragma unroll
        for (int s = 0; s < 16; ++s) ssum += comb[(s << 6) + t];
        float Wj = LOG_B - (Mlds[t] + __logf(ssum));
        Wlds[t] = Wj;
        W[j0 + t] = Wj;
    }
    __syncthreads();
    float4 Wq = make_float4(Wlds[4 * jq + 0], Wlds[4 * jq + 1],
                            Wlds[4 * jq + 2], Wlds[4 * jq + 3]);

    // ---- phase R: per-row partial lse over this block's 64 columns
#pragma unroll
    for (int k = 0; k < 16; ++k) {
        float a0 = tile[k].x + Wq.x;
        float a1 = tile[k].y + Wq.y;
        float a2 = tile[k].z + Wq.z;
        float a3 = tile[k].w + Wq.w;
        float m = fmaxf(fmaxf(a0, a1), fmaxf(a2, a3));
        float s = __expf(a0 - m) + __expf(a1 - m) + __expf(a2 - m) + __expf(a3 - m);
        int i = is + (k << 4);
        m_arr[i * 17 + jq] = m;   // stride 17: ~2-way banks only (free, m136)
        s_arr[i * 17 + jq] = s;
    }
    __syncthreads();
    {   // thread t combines the 16 column-quad partials of row t
        float m = -INFINITY, s = 0.f;
#pragma unroll
        for (int p = 0; p < 16; ++p) {
            float pmv = m_arr[t * 17 + p];
            float psv = s_arr[t * 17 + p];
            float nm = fmaxf(m, pmv);
            s = s * __expf(m - nm) + psv * __expf(pmv - nm);
            m = nm;
        }
        pm[(b << 8) + t] = m;     // contiguous per block, coalesced combine
        ps[(b << 8) + t] = s;
    }

    // ---- last-block combine (threadfence reduction, device scope)
    __threadfence();                       // release: partials -> device scope
    if (t == 0) lastf = (atomicAdd(counter, 1) == 511);
    __syncthreads();
    if (!lastf) return;
    __threadfence();                       // acquire

    {   // thread t: row t; 512 block-partials, 4 interleaved lse chains
        float cm[4] = {-INFINITY, -INFINITY, -INFINITY, -INFINITY};
        float cs[4] = {0.f, 0.f, 0.f, 0.f};
        for (int p = 0; p < 512; p += 4) {
#pragma unroll
            for (int c = 0; c < 4; ++c) {
                float pmv = pm[((p + c) << 8) + t];   // lanes coalesced
                float psv = ps[((p + c) << 8) + t];
                float nm = fmaxf(cm[c], pmv);
                cs[c] = cs[c] * __expf(cm[c] - nm) + psv * __expf(pmv - nm);
                cm[c] = nm;
            }
        }
        float m = cm[0], s = cs[0];
#pragma unroll
        for (int c = 1; c < 4; ++c) {
            float nm = fmaxf(m, cm[c]);
            s = s * __expf(m - nm) + cs[c] * __expf(cm[c] - nm);
            m = nm;
        }
        su[t] = LOG_A - (m + __logf(s));
    }
}

// --------------------------------------------- absorb-step column error -----
// col[j] = exp(lse_i(G+su') + W[j]);  err_col = max_j |col - b|.
// Last block folds the convergence check (active update) -> no sink_check.
__global__ __launch_bounds__(256) void sink_colerr(
    const float* __restrict__ G, const float* __restrict__ su,
    const float* __restrict__ W, unsigned* __restrict__ colerr, int slot,
    int* __restrict__ counter, int* __restrict__ active, int gated)
{
    if (gated && active[0] == 0) return;
    __shared__ float comb[1024];
    __shared__ float Mlds[64];

    const int t  = threadIdx.x;
    const int b  = blockIdx.x;
    const int j0 = b << 6;
    const int jq = t & 15;
    const int is = t >> 4;

    const float4* G4 = (const float4*)G;
    float4 tile[16];
    float  sur[16];
#pragma unroll
    for (int k = 0; k < 16; ++k) {
        int i = is + (k << 4);
        tile[k] = G4[i * 8192 + (j0 >> 2) + jq];
        sur[k]  = su[i];
    }
    float m0 = -INFINITY, m1 = -INFINITY, m2 = -INFINITY, m3 = -INFINITY;
#pragma unroll
    for (int k = 0; k < 16; ++k) {
        m0 = fmaxf(m0, tile[k].x + sur[k]);
        m1 = fmaxf(m1, tile[k].y + sur[k]);
        m2 = fmaxf(m2, tile[k].z + sur[k]);
        m3 = fmaxf(m3, tile[k].w + sur[k]);
    }
    ((float4*)comb)[(is << 4) + jq] = make_float4(m0, m1, m2, m3);
    __syncthreads();
    if (t < 64) {
        float m = -INFINITY;
#pragma unroll
        for (int s = 0; s < 16; ++s) m = fmaxf(m, comb[(s << 6) + t]);
        Mlds[t] = m;
    }
    __syncthreads();
    float4 Mq = make_float4(Mlds[4 * jq + 0], Mlds[4 * jq + 1],
                            Mlds[4 * jq + 2], Mlds[4 * jq + 3]);
    float s0 = 0.f, s1 = 0.f, s2 = 0.f, s3 = 0.f;
#pragma unroll
    for (int k = 0; k < 16; ++k) {
        s0 += __expf(tile[k].x + sur[k] - Mq.x);
        s1 += __expf(tile[k].y + sur[k] - Mq.y);
        s2 += __expf(tile[k].z + sur[k] - Mq.z);
        s3 += __expf(tile[k].w + sur[k] - Mq.w);
    }
    ((float4*)comb)[(is << 4) + jq] = make_float4(s0, s1, s2, s3);
    __syncthreads();
    if (t < 64) {
        float ssum = 0.f;
#pragma unroll
        for (int s = 0; s < 16; ++s) ssum += comb[(s << 6) + t];
        float Aj  = Mlds[t] + __logf(ssum);
        float col = __expf(Aj + W[j0 + t]);
        float d   = fabsf(col - BVAL);
        for (int off = 32; off; off >>= 1) d = fmaxf(d, __shfl_down(d, off));
        if (t == 0) {
            atomicMax(colerr + slot, __float_as_uint(d));  // d >= 0
            __threadfence();
            if (atomicAdd(counter, 1) == 511) {            // last block: check
                __threadfence();
                unsigned e = atomicMax(colerr + slot, 0u); // coherent read
                active[0] = (__uint_as_float(e) > 0.005f) ? 1 : 0;
            }
        }
    }
}

// ------------------------------------------------------------- finalize -----
// transp + loss in one pass, float4 G loads. Block b: 128 cols, 256 rows.
__global__ __launch_bounds__(256) void finalize_k(
    const float* __restrict__ G, const float* __restrict__ su,
    const float* __restrict__ W, const float* __restrict__ nx,
    const float* __restrict__ ny, float* __restrict__ out)
{
    __shared__ float su_lds[256], nx_lds[256];
    __shared__ float red[4];
    const int t = threadIdx.x, b = blockIdx.x;
    const int j0 = b << 7;            // 128-col slab
    const int jq = t & 31;            // float4-col 0..31
    const int ig = t >> 5;            // i-group 0..7
    su_lds[t] = su[t];
    nx_lds[t] = nx[t];
    __syncthreads();

    const float4* G4 = (const float4*)G;
    const float4 Wq  = ((const float4*)W)[(j0 >> 2) + jq];
    const float4 nyq = ((const float4*)ny)[(j0 >> 2) + jq];
    const int jbase = 1 + j0 + (jq << 2);   // +1: loss slot (breaks 16B align)
    float acc = 0.f;
#pragma unroll 4
    for (int it = 0; it < 32; ++it) {
        const int i = ig + (it << 3);
        float4 g = G4[i * 8192 + (j0 >> 2) + jq];
        const float si = su_lds[i], nxi = nx_lds[i];
        float v0 = __expf(g.x + si + Wq.x);
        float v1 = __expf(g.y + si + Wq.y);
        float v2 = __expf(g.z + si + Wq.z);
        float v3 = __expf(g.w + si + Wq.w);
        float* o = out + jbase + (size_t)i * 32768;
        o[0] = v0; o[1] = v1; o[2] = v2; o[3] = v3;
        acc += v0 * (nxi + nyq.x - 0.05f * g.x) +
               v1 * (nxi + nyq.y - 0.05f * g.y) +
               v2 * (nxi + nyq.z - 0.05f * g.z) +
               v3 * (nxi + nyq.w - 0.05f * g.w);
    }
    for (int off = 32; off; off >>= 1) acc += __shfl_down(acc, off);
    if ((t & 63) == 0) red[t >> 6] = acc;
    __syncthreads();
    if (t == 0) atomicAdd(out, red[0] + red[1] + red[2] + red[3]);
}

// ---------------------------------------------------------------- host ------
extern "C" void kernel_launch(void* const* d_in, const int* in_sizes, int n_in,
                              void* d_out, int out_size, void* d_ws, size_t ws_size,
                              hipStream_t stream)
{
    const float* x = (const float*)d_in[0];   // [256, 384]
    const float* y = (const float*)d_in[1];   // [32768, 384]
    float* out = (float*)d_out;               // [1 + 256*32768]

    float* ws   = (float*)d_ws;
    float* G    = ws;                 // 8388608
    float* Wv   = G + 8388608;        // 32768
    float* su   = Wv + 32768;         // 256
    float* nx   = su + 256;           // 256
    float* ny   = nx + 256;           // 32768
    float* pm   = ny + 32768;         // 131072  [block][row]
    float* ps   = pm + 131072;        // 131072
    unsigned* colerr = (unsigned*)(ps + 131072);   // 2
    int* active   = (int*)(colerr + 2);            // 1
    int* counters = active + 1;                    // 128

    init_k<<<8257, 256, 0, stream>>>(x, y, nx, ny, su, colerr, active, counters, out);
    gemm_k<<<dim3(256, 2), 256, 0, stream>>>(x, y, G);

    // iteration 1 (always runs) + absorb error check (check folded in)
    sink_step<<<512, 256, 0, stream>>>(G, su, Wv, pm, ps, counters + 0, active, 0);
    sink_colerr<<<512, 256, 0, stream>>>(G, su, Wv, colerr, 0, counters + 100, active, 0);

    for (int tt = 2; tt <= 100; ++tt) {
        sink_step<<<512, 256, 0, stream>>>(G, su, Wv, pm, ps, counters + tt - 1, active, 1);
        if (tt == 51)   // absorb at cpt_n=51: error check gates the rest
            sink_colerr<<<512, 256, 0, stream>>>(G, su, Wv, colerr, 1, counters + 101, active, 1);
    }

    finalize_k<<<256, 256, 0, stream>>>(G, su, Wv, nx, ny, out);
}

// Round 7
// 387.582 us; speedup vs baseline: 4.4244x; 1.0187x over previous
//
#include <hip/hip_runtime.h>
#include <math.h>

// ---------------------------------------------------------------------------
// Sinkhorn ETP (FASTopic) on MI355X.
// n=256 topics, m=32768 words, D=384.
//
// State reduction (derived from the reference):
//   log_K0[i,j] = G[i,j] + su0[i] + sv0[j],  G = 40 * x@y^T
//   Per iteration:  L1[j] = lse_i(G+su);  W[j] = log_b - L1[j]
//                   L2[i] = lse_j(G+W);   su'[i] = log_a - L2[i]
//   Final: transp[i,j] = exp(G+su[i]+W[j]); M = nx[i]+ny[j]-0.05*G;
//          loss = sum(transp*M)
//
// GEMM: MFMA bf16 exact 3-way truncation split (R5: absmax 1.9e-6).
// R7: two-level lse combine (32 groups of 16 -> final 32). R6's single
// last-block combine pulled 1 MB through one CU (~2 us serialized tail/iter);
// level-1 combines overlap the main phase, serialized tail ~0.4 us.
// Partials packed as float2 (m,s).
// ---------------------------------------------------------------------------

#define N_TOPIC 256
#define N_WORD  32768

static constexpr float LOG_A = -5.545177444479562f;    // log(1/256 + 1e-30)
static constexpr float LOG_B = -10.397207708399179f;   // log(1/32768 + 1e-30)
static constexpr float BVAL  = 3.0517578125e-05f;      // 1/32768

typedef float f32x4 __attribute__((ext_vector_type(4)));
typedef short bf16x8 __attribute__((ext_vector_type(8)));

// ---------------------------------------------------------------- init ------
__global__ __launch_bounds__(256) void init_k(
    const float* __restrict__ x, const float* __restrict__ y,
    float* __restrict__ nx, float* __restrict__ ny, float* __restrict__ su,
    unsigned* __restrict__ colerr, int* __restrict__ active,
    int* __restrict__ counters, float* __restrict__ out)
{
    const int b = blockIdx.x, t = threadIdx.x;
    const int w = t >> 6, l = t & 63;
    if (b < 8192) {                       // ||y_j||^2, 4 rows/block (wave per row)
        const int r = (b << 2) + w;
        const float4* y4 = (const float4*)y;
        float4 v = y4[r * 96 + l];
        float s = v.x * v.x + v.y * v.y + v.z * v.z + v.w * v.w;
        if (l < 32) {
            float4 u = y4[r * 96 + 64 + l];
            s += u.x * u.x + u.y * u.y + u.z * u.z + u.w * u.w;
        }
        for (int off = 32; off; off >>= 1) s += __shfl_down(s, off);
        if (l == 0) ny[r] = s;
    } else if (b < 8256) {                // ||x_i||^2 and su0 = -20*nx
        const int r = ((b - 8192) << 2) + w;
        const float4* x4 = (const float4*)x;
        float4 v = x4[r * 96 + l];
        float s = v.x * v.x + v.y * v.y + v.z * v.z + v.w * v.w;
        if (l < 32) {
            float4 u = x4[r * 96 + 64 + l];
            s += u.x * u.x + u.y * u.y + u.z * u.z + u.w * u.w;
        }
        for (int off = 32; off; off >>= 1) s += __shfl_down(s, off);
        if (l == 0) { nx[r] = s; su[r] = -20.f * s; }
    } else {
        for (int k = t; k < 4096; k += 256) counters[k] = 0;
        if (t == 0) { colerr[0] = 0u; colerr[1] = 0u; active[0] = 1; out[0] = 0.f; }
    }
}

// ---------------------------------------------------------------- gemm ------
// Exact 3-way bf16 truncation split: v = b0 + b1 + b2 (+ r3, |r3|<=2^-27|v|).
static __device__ __forceinline__ void split3(float v, ushort& h0, ushort& h1, ushort& h2)
{
    unsigned u0 = __float_as_uint(v);
    h0 = (ushort)(u0 >> 16);
    float r1 = v - __uint_as_float(u0 & 0xFFFF0000u);
    unsigned u1 = __float_as_uint(r1);
    h1 = (ushort)(u1 >> 16);
    float r2 = r1 - __uint_as_float(u1 & 0xFFFF0000u);
    h2 = (ushort)(__float_as_uint(r2) >> 16);
}

// Block tile 128i x 128j, K-chunks of 32, grid (256 jb, 2 ib) = 512 blocks.
// Frag layouts (m89/m91-verified); y is [j][k] row-major = B^T identical frag.
__global__ __launch_bounds__(256, 1) void gemm_k(
    const float* __restrict__ x, const float* __restrict__ y, float* __restrict__ G)
{
    __shared__ __align__(16) ushort xs0[5120], xs1[5120], xs2[5120];
    __shared__ __align__(16) ushort ys0[5120], ys1[5120], ys2[5120];

    const int t   = threadIdx.x;
    const int jb  = blockIdx.x << 7;   // 128-col slab
    const int ib  = blockIdx.y << 7;   // 128-row slab
    const int w   = t >> 6;            // wave 0..3
    const int ln  = t & 63;
    const int q   = ln >> 4;           // quad 0..3
    const int l15 = ln & 15;

    const float4* x4 = (const float4*)x;
    const float4* y4 = (const float4*)y;

    f32x4 acc[2][8];
#pragma unroll
    for (int mi = 0; mi < 2; ++mi)
#pragma unroll
        for (int nj = 0; nj < 8; ++nj) acc[mi][nj] = (f32x4){0.f, 0.f, 0.f, 0.f};

    for (int kc = 0; kc < 12; ++kc) {
        __syncthreads();
#pragma unroll
        for (int p = 0; p < 4; ++p) {
            const int f  = (t << 2) + p;       // 0..1023 float4 slots
            const int r  = f >> 3, c4 = f & 7; // row, k-quad
            const int o  = r * 40 + (c4 << 2);
            float4 vx = x4[(ib + r) * 96 + (kc << 3) + c4];
            ushort a0,a1,a2,b0,b1,b2,c0,c1,c2,d0,d1,d2;
            split3(vx.x, a0,a1,a2); split3(vx.y, b0,b1,b2);
            split3(vx.z, c0,c1,c2); split3(vx.w, d0,d1,d2);
            *(ushort4*)&xs0[o] = make_ushort4(a0,b0,c0,d0);
            *(ushort4*)&xs1[o] = make_ushort4(a1,b1,c1,d1);
            *(ushort4*)&xs2[o] = make_ushort4(a2,b2,c2,d2);
            float4 vy = y4[(jb + r) * 96 + (kc << 3) + c4];
            split3(vy.x, a0,a1,a2); split3(vy.y, b0,b1,b2);
            split3(vy.z, c0,c1,c2); split3(vy.w, d0,d1,d2);
            *(ushort4*)&ys0[o] = make_ushort4(a0,b0,c0,d0);
            *(ushort4*)&ys1[o] = make_ushort4(a1,b1,c1,d1);
            *(ushort4*)&ys2[o] = make_ushort4(a2,b2,c2,d2);
        }
        __syncthreads();

        bf16x8 A[3][2];
#pragma unroll
        for (int mi = 0; mi < 2; ++mi) {
            const int off = ((w << 5) + (mi << 4) + l15) * 40 + (q << 3);
            A[0][mi] = *(const bf16x8*)&xs0[off];
            A[1][mi] = *(const bf16x8*)&xs1[off];
            A[2][mi] = *(const bf16x8*)&xs2[off];
        }
#pragma unroll
        for (int nj = 0; nj < 8; ++nj) {
            const int off = ((nj << 4) + l15) * 40 + (q << 3);
            bf16x8 B0 = *(const bf16x8*)&ys0[off];
            bf16x8 B1 = *(const bf16x8*)&ys1[off];
            bf16x8 B2 = *(const bf16x8*)&ys2[off];
#pragma unroll
            for (int mi = 0; mi < 2; ++mi) {
                f32x4 c = acc[mi][nj];
                c = __builtin_amdgcn_mfma_f32_16x16x32_bf16(A[0][mi], B0, c, 0, 0, 0);
                c = __builtin_amdgcn_mfma_f32_16x16x32_bf16(A[0][mi], B1, c, 0, 0, 0);
                c = __builtin_amdgcn_mfma_f32_16x16x32_bf16(A[1][mi], B0, c, 0, 0, 0);
                c = __builtin_amdgcn_mfma_f32_16x16x32_bf16(A[1][mi], B1, c, 0, 0, 0);
                c = __builtin_amdgcn_mfma_f32_16x16x32_bf16(A[0][mi], B2, c, 0, 0, 0);
                c = __builtin_amdgcn_mfma_f32_16x16x32_bf16(A[2][mi], B0, c, 0, 0, 0);
                acc[mi][nj] = c;
            }
        }
    }
#pragma unroll
    for (int mi = 0; mi < 2; ++mi) {
        const int gi0 = ib + (w << 5) + (mi << 4) + (q << 2);
#pragma unroll
        for (int nj = 0; nj < 8; ++nj) {
            const int gj = jb + (nj << 4) + l15;
#pragma unroll
            for (int r = 0; r < 4; ++r)
                G[(size_t)(gi0 + r) * 32768 + gj] = 40.f * acc[mi][nj][r];
        }
    }
}

// ------------------------------------------------------------ iteration -----
// One fused Sinkhorn iteration. Block b owns columns [64b, 64b+64).
// Cross-block row-lse combine is two-level: 32 groups of 16 blocks
// (level-1 combine by each group's last arriver, overlaps main phase),
// then the last group folds 32 group-partials -> su'. cnt[0..31]=groups,
// cnt[32]=final. Partials are float2 (m,s), coalesced in [block][row].
__global__ __launch_bounds__(256) void sink_step(
    const float* __restrict__ G, float* __restrict__ su,
    float* __restrict__ W, float2* __restrict__ pms, float2* __restrict__ lms,
    int* __restrict__ cnt, const int* __restrict__ active, int gated)
{
    if (gated && active[0] == 0) return;
    __shared__ float comb[1024];
    __shared__ float Mlds[64];
    __shared__ float Wlds[64];
    __shared__ float m_arr[256 * 17];
    __shared__ float s_arr[256 * 17];
    __shared__ int lastf;

    const int t  = threadIdx.x;
    const int b  = blockIdx.x;
    const int j0 = b << 6;
    const int jq = t & 15;       // column quad 0..15 (4 cols each)
    const int is = t >> 4;       // row subset 0..15 (rows is+16k)

    const float4* G4 = (const float4*)G;
    float4 tile[16];
    float  sur[16];
#pragma unroll
    for (int k = 0; k < 16; ++k) {
        int i = is + (k << 4);
        tile[k] = G4[i * 8192 + (j0 >> 2) + jq];
        sur[k]  = su[i];          // broadcast loads, L1/L2-hot
    }

    // ---- phase C: column logsumexp over i (exact two-pass from registers)
    float m0 = -INFINITY, m1 = -INFINITY, m2 = -INFINITY, m3 = -INFINITY;
#pragma unroll
    for (int k = 0; k < 16; ++k) {
        m0 = fmaxf(m0, tile[k].x + sur[k]);
        m1 = fmaxf(m1, tile[k].y + sur[k]);
        m2 = fmaxf(m2, tile[k].z + sur[k]);
        m3 = fmaxf(m3, tile[k].w + sur[k]);
    }
    ((float4*)comb)[(is << 4) + jq] = make_float4(m0, m1, m2, m3);
    __syncthreads();
    if (t < 64) {
        float m = -INFINITY;
#pragma unroll
        for (int s = 0; s < 16; ++s) m = fmaxf(m, comb[(s << 6) + t]);
        Mlds[t] = m;
    }
    __syncthreads();
    float4 Mq = make_float4(Mlds[4 * jq + 0], Mlds[4 * jq + 1],
                            Mlds[4 * jq + 2], Mlds[4 * jq + 3]);
    float s0 = 0.f, s1 = 0.f, s2 = 0.f, s3 = 0.f;
#pragma unroll
    for (int k = 0; k < 16; ++k) {
        s0 += __expf(tile[k].x + sur[k] - Mq.x);
        s1 += __expf(tile[k].y + sur[k] - Mq.y);
        s2 += __expf(tile[k].z + sur[k] - Mq.z);
        s3 += __expf(tile[k].w + sur[k] - Mq.w);
    }
    ((float4*)comb)[(is << 4) + jq] = make_float4(s0, s1, s2, s3);
    __syncthreads();
    if (t < 64) {
        float ssum = 0.f;
#pragma unroll
        for (int s = 0; s < 16; ++s) ssum += comb[(s << 6) + t];
        float Wj = LOG_B - (Mlds[t] + __logf(ssum));
        Wlds[t] = Wj;
        W[j0 + t] = Wj;
    }
    __syncthreads();
    float4 Wq = make_float4(Wlds[4 * jq + 0], Wlds[4 * jq + 1],
                            Wlds[4 * jq + 2], Wlds[4 * jq + 3]);

    // ---- phase R: per-row partial lse over this block's 64 columns
#pragma unroll
    for (int k = 0; k < 16; ++k) {
        float a0 = tile[k].x + Wq.x;
        float a1 = tile[k].y + Wq.y;
        float a2 = tile[k].z + Wq.z;
        float a3 = tile[k].w + Wq.w;
        float m = fmaxf(fmaxf(a0, a1), fmaxf(a2, a3));
        float s = __expf(a0 - m) + __expf(a1 - m) + __expf(a2 - m) + __expf(a3 - m);
        int i = is + (k << 4);
        m_arr[i * 17 + jq] = m;   // stride 17: ~2-way banks only (free, m136)
        s_arr[i * 17 + jq] = s;
    }
    __syncthreads();
    {   // thread t combines the 16 column-quad partials of row t
        float m = -INFINITY, s = 0.f;
#pragma unroll
        for (int p = 0; p < 16; ++p) {
            float pmv = m_arr[t * 17 + p];
            float psv = s_arr[t * 17 + p];
            float nm = fmaxf(m, pmv);
            s = s * __expf(m - nm) + psv * __expf(pmv - nm);
            m = nm;
        }
        pms[(b << 8) + t] = make_float2(m, s);
    }

    // ---- level 1: last arriver of each 16-block group folds 16 partials
    __threadfence();                       // release partials
    if (t == 0) lastf = (atomicAdd(cnt + (b >> 4), 1) == 15);
    __syncthreads();
    if (!lastf) return;
    __threadfence();                       // acquire

    const int g = b >> 4;
    {
        float cm[4] = {-INFINITY, -INFINITY, -INFINITY, -INFINITY};
        float cs[4] = {0.f, 0.f, 0.f, 0.f};
#pragma unroll
        for (int p = 0; p < 16; p += 4) {
#pragma unroll
            for (int c = 0; c < 4; ++c) {
                float2 v = pms[(((g << 4) + p + c) << 8) + t];
                float nm = fmaxf(cm[c], v.x);
                cs[c] = cs[c] * __expf(cm[c] - nm) + v.y * __expf(v.x - nm);
                cm[c] = nm;
            }
        }
        float m = cm[0], s = cs[0];
#pragma unroll
        for (int c = 1; c < 4; ++c) {
            float nm = fmaxf(m, cm[c]);
            s = s * __expf(m - nm) + cs[c] * __expf(cm[c] - nm);
            m = nm;
        }
        lms[(g << 8) + t] = make_float2(m, s);
    }

    // ---- level 2: last group folds the 32 group-partials -> su'
    __threadfence();
    if (t == 0) lastf = (atomicAdd(cnt + 32, 1) == 31);
    __syncthreads();
    if (!lastf) return;
    __threadfence();

    {
        float cm[4] = {-INFINITY, -INFINITY, -INFINITY, -INFINITY};
        float cs[4] = {0.f, 0.f, 0.f, 0.f};
#pragma unroll
        for (int p = 0; p < 32; p += 4) {
#pragma unroll
            for (int c = 0; c < 4; ++c) {
                float2 v = lms[((p + c) << 8) + t];
                float nm = fmaxf(cm[c], v.x);
                cs[c] = cs[c] * __expf(cm[c] - nm) + v.y * __expf(v.x - nm);
                cm[c] = nm;
            }
        }
        float m = cm[0], s = cs[0];
#pragma unroll
        for (int c = 1; c < 4; ++c) {
            float nm = fmaxf(m, cm[c]);
            s = s * __expf(m - nm) + cs[c] * __expf(cm[c] - nm);
            m = nm;
        }
        su[t] = LOG_A - (m + __logf(s));
    }
}

// --------------------------------------------- absorb-step column error -----
// col[j] = exp(lse_i(G+su') + W[j]);  err_col = max_j |col - b|.
// Last block folds the convergence check (active update).
__global__ __launch_bounds__(256) void sink_colerr(
    const float* __restrict__ G, const float* __restrict__ su,
    const float* __restrict__ W, unsigned* __restrict__ colerr, int slot,
    int* __restrict__ counter, int* __restrict__ active, int gated)
{
    if (gated && active[0] == 0) return;
    __shared__ float comb[1024];
    __shared__ float Mlds[64];

    const int t  = threadIdx.x;
    const int b  = blockIdx.x;
    const int j0 = b << 6;
    const int jq = t & 15;
    const int is = t >> 4;

    const float4* G4 = (const float4*)G;
    float4 tile[16];
    float  sur[16];
#pragma unroll
    for (int k = 0; k < 16; ++k) {
        int i = is + (k << 4);
        tile[k] = G4[i * 8192 + (j0 >> 2) + jq];
        sur[k]  = su[i];
    }
    float m0 = -INFINITY, m1 = -INFINITY, m2 = -INFINITY, m3 = -INFINITY;
#pragma unroll
    for (int k = 0; k < 16; ++k) {
        m0 = fmaxf(m0, tile[k].x + sur[k]);
        m1 = fmaxf(m1, tile[k].y + sur[k]);
        m2 = fmaxf(m2, tile[k].z + sur[k]);
        m3 = fmaxf(m3, tile[k].w + sur[k]);
    }
    ((float4*)comb)[(is << 4) + jq] = make_float4(m0, m1, m2, m3);
    __syncthreads();
    if (t < 64) {
        float m = -INFINITY;
#pragma unroll
        for (int s = 0; s < 16; ++s) m = fmaxf(m, comb[(s << 6) + t]);
        Mlds[t] = m;
    }
    __syncthreads();
    float4 Mq = make_float4(Mlds[4 * jq + 0], Mlds[4 * jq + 1],
                            Mlds[4 * jq + 2], Mlds[4 * jq + 3]);
    float s0 = 0.f, s1 = 0.f, s2 = 0.f, s3 = 0.f;
#pragma unroll
    for (int k = 0; k < 16; ++k) {
        s0 += __expf(tile[k].x + sur[k] - Mq.x);
        s1 += __expf(tile[k].y + sur[k] - Mq.y);
        s2 += __expf(tile[k].z + sur[k] - Mq.z);
        s3 += __expf(tile[k].w + sur[k] - Mq.w);
    }
    ((float4*)comb)[(is << 4) + jq] = make_float4(s0, s1, s2, s3);
    __syncthreads();
    if (t < 64) {
        float ssum = 0.f;
#pragma unroll
        for (int s = 0; s < 16; ++s) ssum += comb[(s << 6) + t];
        float Aj  = Mlds[t] + __logf(ssum);
        float col = __expf(Aj + W[j0 + t]);
        float d   = fabsf(col - BVAL);
        for (int off = 32; off; off >>= 1) d = fmaxf(d, __shfl_down(d, off));
        if (t == 0) {
            atomicMax(colerr + slot, __float_as_uint(d));  // d >= 0
            __threadfence();
            if (atomicAdd(counter, 1) == 511) {            // last block: check
                __threadfence();
                unsigned e = atomicMax(colerr + slot, 0u); // coherent read
                active[0] = (__uint_as_float(e) > 0.005f) ? 1 : 0;
            }
        }
    }
}

// ------------------------------------------------------------- finalize -----
// transp + loss in one pass, float4 G loads. Block b: 128 cols, 256 rows.
__global__ __launch_bounds__(256) void finalize_k(
    const float* __restrict__ G, const float* __restrict__ su,
    const float* __restrict__ W, const float* __restrict__ nx,
    const float* __restrict__ ny, float* __restrict__ out)
{
    __shared__ float su_lds[256], nx_lds[256];
    __shared__ float red[4];
    const int t = threadIdx.x, b = blockIdx.x;
    const int j0 = b << 7;            // 128-col slab
    const int jq = t & 31;            // float4-col 0..31
    const int ig = t >> 5;            // i-group 0..7
    su_lds[t] = su[t];
    nx_lds[t] = nx[t];
    __syncthreads();

    const float4* G4 = (const float4*)G;
    const float4 Wq  = ((const float4*)W)[(j0 >> 2) + jq];
    const float4 nyq = ((const float4*)ny)[(j0 >> 2) + jq];
    const int jbase = 1 + j0 + (jq << 2);   // +1: loss slot (breaks 16B align)
    float acc = 0.f;
#pragma unroll 4
    for (int it = 0; it < 32; ++it) {
        const int i = ig + (it << 3);
        float4 g = G4[i * 8192 + (j0 >> 2) + jq];
        const float si = su_lds[i], nxi = nx_lds[i];
        float v0 = __expf(g.x + si + Wq.x);
        float v1 = __expf(g.y + si + Wq.y);
        float v2 = __expf(g.z + si + Wq.z);
        float v3 = __expf(g.w + si + Wq.w);
        float* o = out + jbase + (size_t)i * 32768;
        o[0] = v0; o[1] = v1; o[2] = v2; o[3] = v3;
        acc += v0 * (nxi + nyq.x - 0.05f * g.x) +
               v1 * (nxi + nyq.y - 0.05f * g.y) +
               v2 * (nxi + nyq.z - 0.05f * g.z) +
               v3 * (nxi + nyq.w - 0.05f * g.w);
    }
    for (int off = 32; off; off >>= 1) acc += __shfl_down(acc, off);
    if ((t & 63) == 0) red[t >> 6] = acc;
    __syncthreads();
    if (t == 0) atomicAdd(out, red[0] + red[1] + red[2] + red[3]);
}

// ---------------------------------------------------------------- host ------
extern "C" void kernel_launch(void* const* d_in, const int* in_sizes, int n_in,
                              void* d_out, int out_size, void* d_ws, size_t ws_size,
                              hipStream_t stream)
{
    const float* x = (const float*)d_in[0];   // [256, 384]
    const float* y = (const float*)d_in[1];   // [32768, 384]
    float* out = (float*)d_out;               // [1 + 256*32768]

    float* ws   = (float*)d_ws;
    float* G    = ws;                 // 8388608
    float* Wv   = G + 8388608;        // 32768
    float* su   = Wv + 32768;         // 256
    float* nx   = su + 256;           // 256
    float* ny   = nx + 256;           // 32768
    float2* pms = (float2*)(ny + 32768);           // 131072 float2 [block][row]
    float2* lms = pms + 131072;                    // 8192 float2  [group][row]
    unsigned* colerr = (unsigned*)(lms + 8192);    // 2
    int* active   = (int*)(colerr + 2);            // 1
    int* counters = active + 1;                    // 4096 (40/iter + colerr)

    init_k<<<8257, 256, 0, stream>>>(x, y, nx, ny, su, colerr, active, counters, out);
    gemm_k<<<dim3(256, 2), 256, 0, stream>>>(x, y, G);

    // iteration 1 (always runs) + absorb error check (check folded in)
    sink_step<<<512, 256, 0, stream>>>(G, su, Wv, pms, lms, counters + 0, active, 0);
    sink_colerr<<<512, 256, 0, stream>>>(G, su, Wv, colerr, 0, counters + 4000, active, 0);

    for (int tt = 2; tt <= 100; ++tt) {
        sink_step<<<512, 256, 0, stream>>>(G, su, Wv, pms, lms,
                                           counters + 40 * (tt - 1), active, 1);
        if (tt == 51)   // absorb at cpt_n=51: error check gates the rest
            sink_colerr<<<512, 256, 0, stream>>>(G, su, Wv, colerr, 1,
                                                 counters + 4001, active, 1);
    }

    finalize_k<<<256, 256, 0, stream>>>(G, su, Wv, nx, ny, out);
}

// Round 8
// 383.724 us; speedup vs baseline: 4.4689x; 1.0101x over previous
//
#include <hip/hip_runtime.h>
#include <math.h>

// ---------------------------------------------------------------------------
// Sinkhorn ETP (FASTopic) on MI355X.
// n=256 topics, m=32768 words, D=384.
//
//   log_K0[i,j] = G[i,j] + su0[i] + sv0[j],  G = 40 * x@y^T
//   Per iteration:  L1[j] = lse_i(G+su);  W[j] = log_b - L1[j]
//                   L2[i] = lse_j(G+W);   su'[i] = log_a - L2[i]
//   Final: transp[i,j] = exp(G+su[i]+W[j]); M = nx[i]+ny[j]-0.05*G;
//          loss = sum(transp*M)
//
// R8: E-reuse fast path (iters 2..100): exp(G+su+W) = E_ij * (b/S_j) where
// E = exp(G+su-M_j) from the column pass, S_j = col sum of E. Phase R = one
// fma/elem, cross-block combine = plain sums. Row sums >= a*b for t>=2
// (W_t = W_{t-1} - log(col/b), col<=1) -> no underflow. Iter 1 keeps the
// log-safe lse kernel (su0 spread ~1000s of nats; orphan rows ~e^-400).
// ---------------------------------------------------------------------------

#define N_TOPIC 256
#define N_WORD  32768

static constexpr float LOG_A = -5.545177444479562f;    // log(1/256 + 1e-30)
static constexpr float LOG_B = -10.397207708399179f;   // log(1/32768 + 1e-30)
static constexpr float BVAL  = 3.0517578125e-05f;      // 1/32768

typedef float f32x4 __attribute__((ext_vector_type(4)));
typedef short bf16x8 __attribute__((ext_vector_type(8)));

// ---------------------------------------------------------------- init ------
__global__ __launch_bounds__(256) void init_k(
    const float* __restrict__ x, const float* __restrict__ y,
    float* __restrict__ nx, float* __restrict__ ny, float* __restrict__ su,
    unsigned* __restrict__ colerr, int* __restrict__ active,
    int* __restrict__ counters, float* __restrict__ out)
{
    const int b = blockIdx.x, t = threadIdx.x;
    const int w = t >> 6, l = t & 63;
    if (b < 8192) {                       // ||y_j||^2, 4 rows/block (wave per row)
        const int r = (b << 2) + w;
        const float4* y4 = (const float4*)y;
        float4 v = y4[r * 96 + l];
        float s = v.x * v.x + v.y * v.y + v.z * v.z + v.w * v.w;
        if (l < 32) {
            float4 u = y4[r * 96 + 64 + l];
            s += u.x * u.x + u.y * u.y + u.z * u.z + u.w * u.w;
        }
        for (int off = 32; off; off >>= 1) s += __shfl_down(s, off);
        if (l == 0) ny[r] = s;
    } else if (b < 8256) {                // ||x_i||^2 and su0 = -20*nx
        const int r = ((b - 8192) << 2) + w;
        const float4* x4 = (const float4*)x;
        float4 v = x4[r * 96 + l];
        float s = v.x * v.x + v.y * v.y + v.z * v.z + v.w * v.w;
        if (l < 32) {
            float4 u = x4[r * 96 + 64 + l];
            s += u.x * u.x + u.y * u.y + u.z * u.z + u.w * u.w;
        }
        for (int off = 32; off; off >>= 1) s += __shfl_down(s, off);
        if (l == 0) { nx[r] = s; su[r] = -20.f * s; }
    } else {
        for (int k = t; k < 4096; k += 256) counters[k] = 0;
        if (t == 0) { colerr[0] = 0u; colerr[1] = 0u; active[0] = 1; out[0] = 0.f; }
    }
}

// ---------------------------------------------------------------- gemm ------
// Exact 3-way bf16 truncation split: v = b0 + b1 + b2 (+ r3, |r3|<=2^-27|v|).
static __device__ __forceinline__ void split3(float v, ushort& h0, ushort& h1, ushort& h2)
{
    unsigned u0 = __float_as_uint(v);
    h0 = (ushort)(u0 >> 16);
    float r1 = v - __uint_as_float(u0 & 0xFFFF0000u);
    unsigned u1 = __float_as_uint(r1);
    h1 = (ushort)(u1 >> 16);
    float r2 = r1 - __uint_as_float(u1 & 0xFFFF0000u);
    h2 = (ushort)(__float_as_uint(r2) >> 16);
}

// Block tile 128i x 128j, K-chunks of 32, grid (256 jb, 2 ib) = 512 blocks.
// Frag layouts (m89/m91-verified); y is [j][k] row-major = B^T identical frag.
__global__ __launch_bounds__(256, 1) void gemm_k(
    const float* __restrict__ x, const float* __restrict__ y, float* __restrict__ G)
{
    __shared__ __align__(16) ushort xs0[5120], xs1[5120], xs2[5120];
    __shared__ __align__(16) ushort ys0[5120], ys1[5120], ys2[5120];

    const int t   = threadIdx.x;
    const int jb  = blockIdx.x << 7;   // 128-col slab
    const int ib  = blockIdx.y << 7;   // 128-row slab
    const int w   = t >> 6;            // wave 0..3
    const int ln  = t & 63;
    const int q   = ln >> 4;           // quad 0..3
    const int l15 = ln & 15;

    const float4* x4 = (const float4*)x;
    const float4* y4 = (const float4*)y;

    f32x4 acc[2][8];
#pragma unroll
    for (int mi = 0; mi < 2; ++mi)
#pragma unroll
        for (int nj = 0; nj < 8; ++nj) acc[mi][nj] = (f32x4){0.f, 0.f, 0.f, 0.f};

    for (int kc = 0; kc < 12; ++kc) {
        __syncthreads();
#pragma unroll
        for (int p = 0; p < 4; ++p) {
            const int f  = (t << 2) + p;       // 0..1023 float4 slots
            const int r  = f >> 3, c4 = f & 7; // row, k-quad
            const int o  = r * 40 + (c4 << 2);
            float4 vx = x4[(ib + r) * 96 + (kc << 3) + c4];
            ushort a0,a1,a2,b0,b1,b2,c0,c1,c2,d0,d1,d2;
            split3(vx.x, a0,a1,a2); split3(vx.y, b0,b1,b2);
            split3(vx.z, c0,c1,c2); split3(vx.w, d0,d1,d2);
            *(ushort4*)&xs0[o] = make_ushort4(a0,b0,c0,d0);
            *(ushort4*)&xs1[o] = make_ushort4(a1,b1,c1,d1);
            *(ushort4*)&xs2[o] = make_ushort4(a2,b2,c2,d2);
            float4 vy = y4[(jb + r) * 96 + (kc << 3) + c4];
            split3(vy.x, a0,a1,a2); split3(vy.y, b0,b1,b2);
            split3(vy.z, c0,c1,c2); split3(vy.w, d0,d1,d2);
            *(ushort4*)&ys0[o] = make_ushort4(a0,b0,c0,d0);
            *(ushort4*)&ys1[o] = make_ushort4(a1,b1,c1,d1);
            *(ushort4*)&ys2[o] = make_ushort4(a2,b2,c2,d2);
        }
        __syncthreads();

        bf16x8 A[3][2];
#pragma unroll
        for (int mi = 0; mi < 2; ++mi) {
            const int off = ((w << 5) + (mi << 4) + l15) * 40 + (q << 3);
            A[0][mi] = *(const bf16x8*)&xs0[off];
            A[1][mi] = *(const bf16x8*)&xs1[off];
            A[2][mi] = *(const bf16x8*)&xs2[off];
        }
#pragma unroll
        for (int nj = 0; nj < 8; ++nj) {
            const int off = ((nj << 4) + l15) * 40 + (q << 3);
            bf16x8 B0 = *(const bf16x8*)&ys0[off];
            bf16x8 B1 = *(const bf16x8*)&ys1[off];
            bf16x8 B2 = *(const bf16x8*)&ys2[off];
#pragma unroll
            for (int mi = 0; mi < 2; ++mi) {
                f32x4 c = acc[mi][nj];
                c = __builtin_amdgcn_mfma_f32_16x16x32_bf16(A[0][mi], B0, c, 0, 0, 0);
                c = __builtin_amdgcn_mfma_f32_16x16x32_bf16(A[0][mi], B1, c, 0, 0, 0);
                c = __builtin_amdgcn_mfma_f32_16x16x32_bf16(A[1][mi], B0, c, 0, 0, 0);
                c = __builtin_amdgcn_mfma_f32_16x16x32_bf16(A[1][mi], B1, c, 0, 0, 0);
                c = __builtin_amdgcn_mfma_f32_16x16x32_bf16(A[0][mi], B2, c, 0, 0, 0);
                c = __builtin_amdgcn_mfma_f32_16x16x32_bf16(A[2][mi], B0, c, 0, 0, 0);
                acc[mi][nj] = c;
            }
        }
    }
#pragma unroll
    for (int mi = 0; mi < 2; ++mi) {
        const int gi0 = ib + (w << 5) + (mi << 4) + (q << 2);
#pragma unroll
        for (int nj = 0; nj < 8; ++nj) {
            const int gj = jb + (nj << 4) + l15;
#pragma unroll
            for (int r = 0; r < 4; ++r)
                G[(size_t)(gi0 + r) * 32768 + gj] = 40.f * acc[mi][nj][r];
        }
    }
}

// -------------------------------------------- iteration (safe, iter 1) ------
// R7 log-safe kernel: lse partials everywhere. Used only for iteration 1,
// where su0 = -20|x|^2 has huge spread and row masses can be ~e^-400.
__global__ __launch_bounds__(256) void sink_step(
    const float* __restrict__ G, float* __restrict__ su,
    float* __restrict__ W, float2* __restrict__ pms, float2* __restrict__ lms,
    int* __restrict__ cnt, const int* __restrict__ active, int gated)
{
    if (gated && active[0] == 0) return;
    __shared__ float comb[1024];
    __shared__ float Mlds[64];
    __shared__ float Wlds[64];
    __shared__ float m_arr[256 * 17];
    __shared__ float s_arr[256 * 17];
    __shared__ int lastf;

    const int t  = threadIdx.x;
    const int b  = blockIdx.x;
    const int j0 = b << 6;
    const int jq = t & 15;
    const int is = t >> 4;

    const float4* G4 = (const float4*)G;
    float4 tile[16];
    float  sur[16];
#pragma unroll
    for (int k = 0; k < 16; ++k) {
        int i = is + (k << 4);
        tile[k] = G4[i * 8192 + (j0 >> 2) + jq];
        sur[k]  = su[i];
    }

    float m0 = -INFINITY, m1 = -INFINITY, m2 = -INFINITY, m3 = -INFINITY;
#pragma unroll
    for (int k = 0; k < 16; ++k) {
        m0 = fmaxf(m0, tile[k].x + sur[k]);
        m1 = fmaxf(m1, tile[k].y + sur[k]);
        m2 = fmaxf(m2, tile[k].z + sur[k]);
        m3 = fmaxf(m3, tile[k].w + sur[k]);
    }
    ((float4*)comb)[(is << 4) + jq] = make_float4(m0, m1, m2, m3);
    __syncthreads();
    if (t < 64) {
        float m = -INFINITY;
#pragma unroll
        for (int s = 0; s < 16; ++s) m = fmaxf(m, comb[(s << 6) + t]);
        Mlds[t] = m;
    }
    __syncthreads();
    float4 Mq = make_float4(Mlds[4 * jq + 0], Mlds[4 * jq + 1],
                            Mlds[4 * jq + 2], Mlds[4 * jq + 3]);
    float s0 = 0.f, s1 = 0.f, s2 = 0.f, s3 = 0.f;
#pragma unroll
    for (int k = 0; k < 16; ++k) {
        s0 += __expf(tile[k].x + sur[k] - Mq.x);
        s1 += __expf(tile[k].y + sur[k] - Mq.y);
        s2 += __expf(tile[k].z + sur[k] - Mq.z);
        s3 += __expf(tile[k].w + sur[k] - Mq.w);
    }
    ((float4*)comb)[(is << 4) + jq] = make_float4(s0, s1, s2, s3);
    __syncthreads();
    if (t < 64) {
        float ssum = 0.f;
#pragma unroll
        for (int s = 0; s < 16; ++s) ssum += comb[(s << 6) + t];
        float Wj = LOG_B - (Mlds[t] + __logf(ssum));
        Wlds[t] = Wj;
        W[j0 + t] = Wj;
    }
    __syncthreads();
    float4 Wq = make_float4(Wlds[4 * jq + 0], Wlds[4 * jq + 1],
                            Wlds[4 * jq + 2], Wlds[4 * jq + 3]);

#pragma unroll
    for (int k = 0; k < 16; ++k) {
        float a0 = tile[k].x + Wq.x;
        float a1 = tile[k].y + Wq.y;
        float a2 = tile[k].z + Wq.z;
        float a3 = tile[k].w + Wq.w;
        float m = fmaxf(fmaxf(a0, a1), fmaxf(a2, a3));
        float s = __expf(a0 - m) + __expf(a1 - m) + __expf(a2 - m) + __expf(a3 - m);
        int i = is + (k << 4);
        m_arr[i * 17 + jq] = m;
        s_arr[i * 17 + jq] = s;
    }
    __syncthreads();
    {
        float m = -INFINITY, s = 0.f;
#pragma unroll
        for (int p = 0; p < 16; ++p) {
            float pmv = m_arr[t * 17 + p];
            float psv = s_arr[t * 17 + p];
            float nm = fmaxf(m, pmv);
            s = s * __expf(m - nm) + psv * __expf(pmv - nm);
            m = nm;
        }
        pms[(b << 8) + t] = make_float2(m, s);
    }

    __threadfence();
    if (t == 0) lastf = (atomicAdd(cnt + (b >> 4), 1) == 15);
    __syncthreads();
    if (!lastf) return;
    __threadfence();

    const int g = b >> 4;
    {
        float cm[4] = {-INFINITY, -INFINITY, -INFINITY, -INFINITY};
        float cs[4] = {0.f, 0.f, 0.f, 0.f};
#pragma unroll
        for (int p = 0; p < 16; p += 4) {
#pragma unroll
            for (int c = 0; c < 4; ++c) {
                float2 v = pms[(((g << 4) + p + c) << 8) + t];
                float nm = fmaxf(cm[c], v.x);
                cs[c] = cs[c] * __expf(cm[c] - nm) + v.y * __expf(v.x - nm);
                cm[c] = nm;
            }
        }
        float m = cm[0], s = cs[0];
#pragma unroll
        for (int c = 1; c < 4; ++c) {
            float nm = fmaxf(m, cm[c]);
            s = s * __expf(m - nm) + cs[c] * __expf(cm[c] - nm);
            m = nm;
        }
        lms[(g << 8) + t] = make_float2(m, s);
    }

    __threadfence();
    if (t == 0) lastf = (atomicAdd(cnt + 32, 1) == 31);
    __syncthreads();
    if (!lastf) return;
    __threadfence();

    {
        float cm[4] = {-INFINITY, -INFINITY, -INFINITY, -INFINITY};
        float cs[4] = {0.f, 0.f, 0.f, 0.f};
#pragma unroll
        for (int p = 0; p < 32; p += 4) {
#pragma unroll
            for (int c = 0; c < 4; ++c) {
                float2 v = lms[((p + c) << 8) + t];
                float nm = fmaxf(cm[c], v.x);
                cs[c] = cs[c] * __expf(cm[c] - nm) + v.y * __expf(v.x - nm);
                cm[c] = nm;
            }
        }
        float m = cm[0], s = cs[0];
#pragma unroll
        for (int c = 1; c < 4; ++c) {
            float nm = fmaxf(m, cm[c]);
            s = s * __expf(m - nm) + cs[c] * __expf(cm[c] - nm);
            m = nm;
        }
        su[t] = LOG_A - (m + __logf(s));
    }
}

// -------------------------------------------- iteration (fast, 2..100) ------
// E-reuse: tile := exp((G+su) - M_j) after the column pass; phase R is one
// fma/elem vs 1/S_j; cross-block combine = plain sums (row sums >= a*b).
// su'[i] = LOG_A - LOG_B + su[i] - log(tot_i), tot_i = sum_j E_ij / S_j.
__global__ __launch_bounds__(256) void sink_fast(
    const float* __restrict__ G, float* __restrict__ su,
    float* __restrict__ W, float* __restrict__ prow, float* __restrict__ lrow,
    int* __restrict__ cnt, const int* __restrict__ active)
{
    if (active[0] == 0) return;
    __shared__ float su_lds[256];
    __shared__ float comb[1024];
    __shared__ float Mlds[64];
    __shared__ float ecol[64];
    __shared__ float s_arr[256 * 17];
    __shared__ int lastf;

    const int t  = threadIdx.x;
    const int b  = blockIdx.x;
    const int j0 = b << 6;
    const int jq = t & 15;
    const int is = t >> 4;

    su_lds[t] = su[t];
    __syncthreads();

    const float4* G4 = (const float4*)G;
    float4 tile[16];
#pragma unroll
    for (int k = 0; k < 16; ++k) {
        int i = is + (k << 4);
        float4 g = G4[i * 8192 + (j0 >> 2) + jq];
        float s = su_lds[i];
        tile[k] = make_float4(g.x + s, g.y + s, g.z + s, g.w + s);
    }

    // column max over i
    float m0 = -INFINITY, m1 = -INFINITY, m2 = -INFINITY, m3 = -INFINITY;
#pragma unroll
    for (int k = 0; k < 16; ++k) {
        m0 = fmaxf(m0, tile[k].x);
        m1 = fmaxf(m1, tile[k].y);
        m2 = fmaxf(m2, tile[k].z);
        m3 = fmaxf(m3, tile[k].w);
    }
    ((float4*)comb)[(is << 4) + jq] = make_float4(m0, m1, m2, m3);
    __syncthreads();
    if (t < 64) {
        float m = -INFINITY;
#pragma unroll
        for (int s = 0; s < 16; ++s) m = fmaxf(m, comb[(s << 6) + t]);
        Mlds[t] = m;
    }
    __syncthreads();
    float4 Mq = make_float4(Mlds[4 * jq + 0], Mlds[4 * jq + 1],
                            Mlds[4 * jq + 2], Mlds[4 * jq + 3]);

    // E = exp(tile - M), column sums S
    float s0 = 0.f, s1 = 0.f, s2 = 0.f, s3 = 0.f;
#pragma unroll
    for (int k = 0; k < 16; ++k) {
        tile[k].x = __expf(tile[k].x - Mq.x); s0 += tile[k].x;
        tile[k].y = __expf(tile[k].y - Mq.y); s1 += tile[k].y;
        tile[k].z = __expf(tile[k].z - Mq.z); s2 += tile[k].z;
        tile[k].w = __expf(tile[k].w - Mq.w); s3 += tile[k].w;
    }
    ((float4*)comb)[(is << 4) + jq] = make_float4(s0, s1, s2, s3);
    __syncthreads();
    if (t < 64) {
        float ssum = 0.f;
#pragma unroll
        for (int s = 0; s < 16; ++s) ssum += comb[(s << 6) + t];
        W[j0 + t] = LOG_B - (Mlds[t] + __logf(ssum));
        ecol[t]   = 1.0f / ssum;            // = exp(W+M)/b
    }
    __syncthreads();
    float4 Eq = make_float4(ecol[4 * jq + 0], ecol[4 * jq + 1],
                            ecol[4 * jq + 2], ecol[4 * jq + 3]);

    // phase R: row partial = dot(E_rowslice, 1/S)
#pragma unroll
    for (int k = 0; k < 16; ++k) {
        float r = tile[k].x * Eq.x + tile[k].y * Eq.y +
                  tile[k].z * Eq.z + tile[k].w * Eq.w;
        s_arr[(is + (k << 4)) * 17 + jq] = r;
    }
    __syncthreads();
    {
        float s = 0.f;
#pragma unroll
        for (int p = 0; p < 16; ++p) s += s_arr[t * 17 + p];
        prow[(b << 8) + t] = s;
    }

    // two-level plain-sum combine
    __threadfence();
    if (t == 0) lastf = (atomicAdd(cnt + (b >> 4), 1) == 15);
    __syncthreads();
    if (!lastf) return;
    __threadfence();

    const int g = b >> 4;
    {
        float acc = 0.f;
#pragma unroll
        for (int p = 0; p < 16; ++p) acc += prow[(((g << 4) + p) << 8) + t];
        lrow[(g << 8) + t] = acc;
    }
    __threadfence();
    if (t == 0) lastf = (atomicAdd(cnt + 32, 1) == 31);
    __syncthreads();
    if (!lastf) return;
    __threadfence();
    {
        float tot = 0.f;
#pragma unroll
        for (int p = 0; p < 32; ++p) tot += lrow[(p << 8) + t];
        su[t] = (LOG_A - LOG_B) + su_lds[t] - __logf(tot);
    }
}

// --------------------------------------------- absorb-step column error -----
__global__ __launch_bounds__(256) void sink_colerr(
    const float* __restrict__ G, const float* __restrict__ su,
    const float* __restrict__ W, unsigned* __restrict__ colerr, int slot,
    int* __restrict__ counter, int* __restrict__ active, int gated)
{
    if (gated && active[0] == 0) return;
    __shared__ float comb[1024];
    __shared__ float Mlds[64];

    const int t  = threadIdx.x;
    const int b  = blockIdx.x;
    const int j0 = b << 6;
    const int jq = t & 15;
    const int is = t >> 4;

    const float4* G4 = (const float4*)G;
    float4 tile[16];
    float  sur[16];
#pragma unroll
    for (int k = 0; k < 16; ++k) {
        int i = is + (k << 4);
        tile[k] = G4[i * 8192 + (j0 >> 2) + jq];
        sur[k]  = su[i];
    }
    float m0 = -INFINITY, m1 = -INFINITY, m2 = -INFINITY, m3 = -INFINITY;
#pragma unroll
    for (int k = 0; k < 16; ++k) {
        m0 = fmaxf(m0, tile[k].x + sur[k]);
        m1 = fmaxf(m1, tile[k].y + sur[k]);
        m2 = fmaxf(m2, tile[k].z + sur[k]);
        m3 = fmaxf(m3, tile[k].w + sur[k]);
    }
    ((float4*)comb)[(is << 4) + jq] = make_float4(m0, m1, m2, m3);
    __syncthreads();
    if (t < 64) {
        float m = -INFINITY;
#pragma unroll
        for (int s = 0; s < 16; ++s) m = fmaxf(m, comb[(s << 6) + t]);
        Mlds[t] = m;
    }
    __syncthreads();
    float4 Mq = make_float4(Mlds[4 * jq + 0], Mlds[4 * jq + 1],
                            Mlds[4 * jq + 2], Mlds[4 * jq + 3]);
    float s0 = 0.f, s1 = 0.f, s2 = 0.f, s3 = 0.f;
#pragma unroll
    for (int k = 0; k < 16; ++k) {
        s0 += __expf(tile[k].x + sur[k] - Mq.x);
        s1 += __expf(tile[k].y + sur[k] - Mq.y);
        s2 += __expf(tile[k].z + sur[k] - Mq.z);
        s3 += __expf(tile[k].w + sur[k] - Mq.w);
    }
    ((float4*)comb)[(is << 4) + jq] = make_float4(s0, s1, s2, s3);
    __syncthreads();
    if (t < 64) {
        float ssum = 0.f;
#pragma unroll
        for (int s = 0; s < 16; ++s) ssum += comb[(s << 6) + t];
        float Aj  = Mlds[t] + __logf(ssum);
        float col = __expf(Aj + W[j0 + t]);
        float d   = fabsf(col - BVAL);
        for (int off = 32; off; off >>= 1) d = fmaxf(d, __shfl_down(d, off));
        if (t == 0) {
            atomicMax(colerr + slot, __float_as_uint(d));
            __threadfence();
            if (atomicAdd(counter, 1) == 511) {
                __threadfence();
                unsigned e = atomicMax(colerr + slot, 0u);
                active[0] = (__uint_as_float(e) > 0.005f) ? 1 : 0;
            }
        }
    }
}

// ------------------------------------------------------------- finalize -----
__global__ __launch_bounds__(256) void finalize_k(
    const float* __restrict__ G, const float* __restrict__ su,
    const float* __restrict__ W, const float* __restrict__ nx,
    const float* __restrict__ ny, float* __restrict__ out)
{
    __shared__ float su_lds[256], nx_lds[256];
    __shared__ float red[4];
    const int t = threadIdx.x, b = blockIdx.x;
    const int j0 = b << 7;
    const int jq = t & 31;
    const int ig = t >> 5;
    su_lds[t] = su[t];
    nx_lds[t] = nx[t];
    __syncthreads();

    const float4* G4 = (const float4*)G;
    const float4 Wq  = ((const float4*)W)[(j0 >> 2) + jq];
    const float4 nyq = ((const float4*)ny)[(j0 >> 2) + jq];
    const int jbase = 1 + j0 + (jq << 2);
    float acc = 0.f;
#pragma unroll 4
    for (int it = 0; it < 32; ++it) {
        const int i = ig + (it << 3);
        float4 g = G4[i * 8192 + (j0 >> 2) + jq];
        const float si = su_lds[i], nxi = nx_lds[i];
        float v0 = __expf(g.x + si + Wq.x);
        float v1 = __expf(g.y + si + Wq.y);
        float v2 = __expf(g.z + si + Wq.z);
        float v3 = __expf(g.w + si + Wq.w);
        float* o = out + jbase + (size_t)i * 32768;
        o[0] = v0; o[1] = v1; o[2] = v2; o[3] = v3;
        acc += v0 * (nxi + nyq.x - 0.05f * g.x) +
               v1 * (nxi + nyq.y - 0.05f * g.y) +
               v2 * (nxi + nyq.z - 0.05f * g.z) +
               v3 * (nxi + nyq.w - 0.05f * g.w);
    }
    for (int off = 32; off; off >>= 1) acc += __shfl_down(acc, off);
    if ((t & 63) == 0) red[t >> 6] = acc;
    __syncthreads();
    if (t == 0) atomicAdd(out, red[0] + red[1] + red[2] + red[3]);
}

// ---------------------------------------------------------------- host ------
extern "C" void kernel_launch(void* const* d_in, const int* in_sizes, int n_in,
                              void* d_out, int out_size, void* d_ws, size_t ws_size,
                              hipStream_t stream)
{
    const float* x = (const float*)d_in[0];   // [256, 384]
    const float* y = (const float*)d_in[1];   // [32768, 384]
    float* out = (float*)d_out;               // [1 + 256*32768]

    float* ws   = (float*)d_ws;
    float* G    = ws;                 // 8388608
    float* Wv   = G + 8388608;        // 32768
    float* su   = Wv + 32768;         // 256
    float* nx   = su + 256;           // 256
    float* ny   = nx + 256;           // 32768
    float2* pms = (float2*)(ny + 32768);           // 131072 float2 (iter 1)
    float2* lms = pms + 131072;                    // 8192 float2
    float* prow = (float*)(lms + 8192);            // 131072 (iters 2+)
    float* lrow = prow + 131072;                   // 8192
    unsigned* colerr = (unsigned*)(lrow + 8192);   // 2
    int* active   = (int*)(colerr + 2);            // 1
    int* counters = active + 1;                    // 4096

    init_k<<<8257, 256, 0, stream>>>(x, y, nx, ny, su, colerr, active, counters, out);
    gemm_k<<<dim3(256, 2), 256, 0, stream>>>(x, y, G);

    // iteration 1 (log-safe) + absorb error check (check folded in)
    sink_step<<<512, 256, 0, stream>>>(G, su, Wv, pms, lms, counters + 0, active, 0);
    sink_colerr<<<512, 256, 0, stream>>>(G, su, Wv, colerr, 0, counters + 4000, active, 0);

    for (int tt = 2; tt <= 100; ++tt) {
        sink_fast<<<512, 256, 0, stream>>>(G, su, Wv, prow, lrow,
                                           counters + 40 * (tt - 1), active);
        if (tt == 51)   // absorb at cpt_n=51: error check gates the rest
            sink_colerr<<<512, 256, 0, stream>>>(G, su, Wv, colerr, 1,
                                                 counters + 4001, active, 1);
    }

    finalize_k<<<256, 256, 0, stream>>>(G, su, Wv, nx, ny, out);
}